// Round 7
// baseline (753.339 us; speedup 1.0000x reference)
//
#include <hip/hip_runtime.h>
#include <math.h>

// Problem constants (from setup_inputs)
#define BATCH 256
#define NQ 30
#define NK 100
#define HID 512
#define WORD 300
#define KIN 900          // WORD*3
#define KP 928           // KIN padded to multiple of 32
#define NANS 32000
#define NOUT 300
#define NOUTP 384        // NOUT padded to multiple of 128 (MFMA N-tile)
#define NLAYERS 3
#define MQT (BATCH * NQ)   // 7680
#define MKT (BATCH * NK)   // 25600
#define SCALE 0.044194173824159216f  // 1/sqrt(512)

typedef __attribute__((ext_vector_type(8))) short bf16x8;
typedef __attribute__((ext_vector_type(4))) float f32x4;
typedef unsigned short ushort_t;

__device__ __forceinline__ unsigned short f2bf(float f) {
  unsigned int u = __float_as_uint(f);
  u = (u + 0x7FFF + ((u >> 16) & 1)) >> 16;  // RNE
  return (unsigned short)u;
}
__device__ __forceinline__ float bf2f(unsigned short s) {
  return __uint_as_float(((unsigned int)s) << 16);
}

typedef const __attribute__((address_space(1))) unsigned int* gas_u32;
typedef __attribute__((address_space(3))) unsigned int* las_u32;
__device__ __forceinline__ void gld_lds16(const void* g, void* l) {
  __builtin_amdgcn_global_load_lds((gas_u32)g, (las_u32)l, 16, 0, 0);
}

// bijective XCD swizzle (m204)
__device__ __forceinline__ int xcd_swz_linear() {
  const int nwg = gridDim.x * gridDim.y;
  const int orig = blockIdx.y * gridDim.x + blockIdx.x;
  const int q = nwg >> 3, r = nwg & 7;
  const int xcd = orig & 7, idx = orig >> 3;
  return (xcd < r ? xcd * (q + 1) : r * (q + 1) + (xcd - r) * q) + idx;
}

// ---------------- reduction helpers ----------------
__device__ __forceinline__ float waveReduceSum(float v) {
#pragma unroll
  for (int o = 32; o > 0; o >>= 1) v += __shfl_xor(v, o);
  return v;
}
__device__ __forceinline__ float waveReduceMax(float v) {
#pragma unroll
  for (int o = 32; o > 0; o >>= 1) v = fmaxf(v, __shfl_xor(v, o));
  return v;
}
__device__ __forceinline__ float2 waveReduceSum2(float2 v) {
#pragma unroll
  for (int o = 32; o > 0; o >>= 1) {
    v.x += __shfl_xor(v.x, o);
    v.y += __shfl_xor(v.y, o);
  }
  return v;
}
__device__ float2 blockReduceSum256x2(float2 v) {
  __shared__ float2 sm2[4];
  int lane = threadIdx.x & 63, w = threadIdx.x >> 6;
  v = waveReduceSum2(v);
  if (lane == 0) sm2[w] = v;
  __syncthreads();
  float2 r;
  r.x = sm2[0].x + sm2[1].x + sm2[2].x + sm2[3].x;
  r.y = sm2[0].y + sm2[1].y + sm2[2].y + sm2[3].y;
  __syncthreads();
  return r;
}
__device__ float blockReduceSum512(float v) {
  __shared__ float sm[8];
  int lane = threadIdx.x & 63, w = threadIdx.x >> 6;
  v = waveReduceSum(v);
  if (lane == 0) sm[w] = v;
  __syncthreads();
  float r = 0.f;
#pragma unroll
  for (int i = 0; i < 8; ++i) r += sm[i];
  __syncthreads();
  return r;
}
__device__ float blockReduceMax512(float v) {
  __shared__ float sm[8];
  int lane = threadIdx.x & 63, w = threadIdx.x >> 6;
  v = waveReduceMax(v);
  if (lane == 0) sm[w] = v;
  __syncthreads();
  float r = -3.4e38f;
#pragma unroll
  for (int i = 0; i < 8; ++i) r = fmaxf(r, sm[i]);
  __syncthreads();
  return r;
}

// ---------------- fused-gather 8-element bf16 pack ----------------
__device__ __forceinline__ bf16x8 gather8(int id0, int id1, int id2, int kb,
                                          const float* __restrict__ emb) {
  union { ushort_t u[8]; bf16x8 v; } pk;
  if (kb >= KIN) {
#pragma unroll
    for (int j = 0; j < 8; ++j) pk.u[j] = 0;
    return pk.v;
  }
  const int n0 = (kb >= 600) ? 2 : ((kb >= 300) ? 1 : 0);
  const int ke = kb + 7;
  const int n7 = (ke >= 600) ? 2 : ((ke >= 300) ? 1 : 0);
  if (n0 == n7 && ke < KIN) {
    const int id = (n0 == 0) ? id0 : ((n0 == 1) ? id1 : id2);
    const float* s = emb + (size_t)id * 300 + (kb - n0 * 300);  // 16B aligned
    float4 v0 = *(const float4*)s;
    float4 v1 = *(const float4*)(s + 4);
    float vv[8] = {v0.x, v0.y, v0.z, v0.w, v1.x, v1.y, v1.z, v1.w};
#pragma unroll
    for (int j = 0; j < 8; ++j) {
      float t = vv[j];
      if (t != t) t = 0.f;
      pk.u[j] = f2bf(t);
    }
  } else {
#pragma unroll
    for (int j = 0; j < 8; ++j) {
      const int kk = kb + j;
      if (kk >= KIN) { pk.u[j] = 0; continue; }
      const int nd = (kk >= 600) ? 2 : ((kk >= 300) ? 1 : 0);
      const int id = (nd == 0) ? id0 : ((nd == 1) ? id1 : id2);
      float t = emb[(size_t)id * 300 + kk - nd * 300];
      if (t != t) t = 0.f;
      pk.u[j] = f2bf(t);
    }
  }
  return pk.v;
}

// ---------------- bf16 MFMA GEMM (dual operand-set, XCD-swizzled) ----------
// For by < M1b: set1; else set2 rebased. C = A @ Bt^T (+bias[clamped at nbias]).
// AGATHER: A is the virtual gathered/cast embedding matrix (ids + emb).
// ZC0: zero col 0 (fused proj_tan0). RELU: epilogue relu.
template <int AGATHER, int BIAS, int OUTF32, int OUTBF16, int ZC0, int RELU>
__global__ __launch_bounds__(256) void mfma_gemm2(
    const ushort_t* __restrict__ A1, const int* __restrict__ ids1,
    const ushort_t* __restrict__ Bt1, const float* __restrict__ bias1,
    float* __restrict__ C1, ushort_t* __restrict__ Cb1, int M1b,
    const ushort_t* __restrict__ A2, const int* __restrict__ ids2,
    const ushort_t* __restrict__ Bt2, const float* __restrict__ bias2,
    float* __restrict__ C2, ushort_t* __restrict__ Cb2,
    const float* __restrict__ emb, int N, int K, int nbias) {
  __shared__ __align__(16) ushort_t Abuf[128 * 32];
  __shared__ __align__(16) ushort_t Bbuf[128 * 32];
  const int wg = xcd_swz_linear();
  const int bx = wg % gridDim.x, by = wg / gridDim.x;
  const bool sel = (by >= M1b);
  const ushort_t* A = sel ? A2 : A1;
  const ushort_t* Bt = sel ? Bt2 : Bt1;
  const float* bias = sel ? bias2 : bias1;
  float* C = sel ? C2 : C1;
  ushort_t* Cb = sel ? Cb2 : Cb1;
  const int row0 = (sel ? (by - M1b) : by) * 128;
  const int col0 = bx * 128;

  const int tid = threadIdx.x;
  const int lane = tid & 63, w = tid >> 6;
  const int wr = w >> 1, wc = w & 1;
  const int s_r = lane & 15, s_kq = lane >> 4;

  const size_t a_src0 = (size_t)(row0 + (w * 2 + 0) * 16 + s_r) * K + s_kq * 8;
  const size_t a_src1 = (size_t)(row0 + (w * 2 + 1) * 16 + s_r) * K + s_kq * 8;
  const size_t b_src0 = (size_t)(col0 + (w * 2 + 0) * 16 + s_r) * K + s_kq * 8;
  const size_t b_src1 = (size_t)(col0 + (w * 2 + 1) * 16 + s_r) * K + s_kq * 8;
  ushort_t* a_dst0 = Abuf + (w * 2 + 0) * 512;
  ushort_t* a_dst1 = Abuf + (w * 2 + 1) * 512;
  ushort_t* b_dst0 = Bbuf + (w * 2 + 0) * 512;
  ushort_t* b_dst1 = Bbuf + (w * 2 + 1) * 512;

  // gather-mode: hoist the 3 node-ids per staged row out of the K loop
  int idA0[3] = {0, 0, 0}, idA1[3] = {0, 0, 0};
  if (AGATHER) {
    const int* idsSel = sel ? ids2 : ids1;
    const int m0 = row0 + (w * 2 + 0) * 16 + s_r;
    const int m1 = row0 + (w * 2 + 1) * 16 + s_r;
#pragma unroll
    for (int j = 0; j < 3; ++j) {
      idA0[j] = idsSel[m0 * 3 + j];
      idA1[j] = idsSel[m1 * 3 + j];
    }
  }

  f32x4 acc[4][4];
#pragma unroll
  for (int i = 0; i < 4; ++i)
#pragma unroll
    for (int j = 0; j < 4; ++j) acc[i][j] = (f32x4){0.f, 0.f, 0.f, 0.f};

  for (int k0 = 0; k0 < K; k0 += 32) {
    gld_lds16(Bt + b_src0 + k0, b_dst0);
    gld_lds16(Bt + b_src1 + k0, b_dst1);
    if (AGATHER) {
      const int kb = k0 + s_kq * 8;
      *(bf16x8*)(a_dst0 + lane * 8) = gather8(idA0[0], idA0[1], idA0[2], kb, emb);
      *(bf16x8*)(a_dst1 + lane * 8) = gather8(idA1[0], idA1[1], idA1[2], kb, emb);
    } else {
      gld_lds16(A + a_src0 + k0, a_dst0);
      gld_lds16(A + a_src1 + k0, a_dst1);
    }
    __syncthreads();
    bf16x8 af[4], bfr[4];
#pragma unroll
    for (int mi = 0; mi < 4; ++mi)
      af[mi] = *(const bf16x8*)(Abuf + (wr * 4 + mi) * 512 + lane * 8);
#pragma unroll
    for (int nj = 0; nj < 4; ++nj)
      bfr[nj] = *(const bf16x8*)(Bbuf + (wc * 4 + nj) * 512 + lane * 8);
#pragma unroll
    for (int mi = 0; mi < 4; ++mi)
#pragma unroll
      for (int nj = 0; nj < 4; ++nj)
        acc[mi][nj] = __builtin_amdgcn_mfma_f32_16x16x32_bf16(
            af[mi], bfr[nj], acc[mi][nj], 0, 0, 0);
    __syncthreads();
  }

#pragma unroll
  for (int nj = 0; nj < 4; ++nj) {
    const int n = col0 + wc * 64 + nj * 16 + (lane & 15);
    const float bb = BIAS ? ((n < nbias) ? bias[n] : 0.f) : 0.f;
#pragma unroll
    for (int mi = 0; mi < 4; ++mi) {
      f32x4 v = acc[mi][nj];
#pragma unroll
      for (int r = 0; r < 4; ++r) {
        const int m = row0 + wr * 64 + mi * 16 + (lane >> 4) * 4 + r;
        float val = v[r] + bb;
        if (RELU) val = fmaxf(val, 0.f);
        if (ZC0 && n == 0) val = 0.f;
        if (OUTF32) C[(size_t)m * N + n] = val;
        if (OUTBF16) Cb[(size_t)m * N + n] = f2bf(val);
      }
    }
  }
}

// ---------------- pre-cast kernels ----------------
// merged transpose-cast, 10 jobs:
// z=0 q2h, z=1 k2h, z=2..4 Wk[i], z=5..7 Wq[i], z=8 p1w, z=9 p2w
__global__ __launch_bounds__(256) void tcast10_k(
    const float* __restrict__ q2h_w, const float* __restrict__ k2h_w,
    const float* __restrict__ Wk, const float* __restrict__ Wq,
    const float* __restrict__ p1w, const float* __restrict__ p2w,
    ushort_t* __restrict__ q2h_wt, ushort_t* __restrict__ k2h_wt,
    ushort_t* __restrict__ Wkt, ushort_t* __restrict__ Wqt,
    ushort_t* __restrict__ p1wt, ushort_t* __restrict__ p2wt) {
  const int z = blockIdx.z;
  const float* src;
  ushort_t* dst;
  int R, Cc, Rp, Cp;
  if (z == 0)      { src = q2h_w; dst = q2h_wt; R = KIN;  Cc = HID;  Rp = KP;   Cp = HID; }
  else if (z == 1) { src = k2h_w; dst = k2h_wt; R = KIN;  Cc = HID;  Rp = KP;   Cp = HID; }
  else if (z < 5)  { int i = z - 2; src = Wk + (size_t)i * HID * HID; dst = Wkt + (size_t)i * HID * HID; R = HID; Cc = HID; Rp = HID; Cp = HID; }
  else if (z < 8)  { int i = z - 5; src = Wq + (size_t)i * HID * HID; dst = Wqt + (size_t)i * HID * HID; R = HID; Cc = HID; Rp = HID; Cp = HID; }
  else if (z == 8) { src = p1w; dst = p1wt; R = 1024; Cc = HID;  Rp = 1024; Cp = HID; }
  else             { src = p2w; dst = p2wt; R = HID;  Cc = NOUT; Rp = HID;  Cp = NOUTP; }
  const int r0 = blockIdx.y * 32, c0 = blockIdx.x * 32;
  if (r0 >= Rp || c0 >= Cp) return;
  __shared__ float t[32][33];
  const int tx = threadIdx.x & 31, ty = threadIdx.x >> 5;
#pragma unroll
  for (int i = 0; i < 4; ++i) {
    int r = r0 + ty + i * 8, c = c0 + tx;
    t[ty + i * 8][tx] = (r < R && c < Cc) ? src[(size_t)r * Cc + c] : 0.f;
  }
  __syncthreads();
#pragma unroll
  for (int i = 0; i < 4; ++i) {
    int c = c0 + ty + i * 8, r = r0 + tx;
    if (c < Cp && r < Rp) dst[(size_t)c * Rp + r] = f2bf(t[tx][ty + i * 8]);
  }
}

// src [R][C] f32 -> dst [R][Cp] bf16 (pad cols with 0)
__global__ __launch_bounds__(128) void cast_pad_rows_k(
    const float* __restrict__ src, ushort_t* __restrict__ dst, int C, int Cp) {
  const int r = blockIdx.x, t = threadIdx.x;
  const int k = t * 4;
  if (k >= Cp) return;
  ushort4 o = make_ushort4(0, 0, 0, 0);
  if (k < C) {
    float4 v = *(const float4*)(src + (size_t)r * C + k);
    o = make_ushort4(f2bf(v.x), f2bf(v.y), f2bf(v.z), f2bf(v.w));
  }
  *(ushort4*)(dst + (size_t)r * Cp + k) = o;
}

// ---------------- fused attention (one block per batch) ----------------
__global__ __launch_bounds__(256) void att_fused_k(
    const ushort_t* __restrict__ kp, const ushort_t* __restrict__ qp,
    const ushort_t* __restrict__ qtb_old, const float* __restrict__ Xq_old,
    float* __restrict__ Xq_new, ushort_t* __restrict__ qtb_new,
    float* __restrict__ Xk, ushort_t* __restrict__ Xkb) {
  const int b = blockIdx.x;
  __shared__ float S_lds[NK][33];        // scores -> Pk in place
  __shared__ float Pq[NQ][NK + 4];
  __shared__ __align__(16) ushort_t qts[NQ * HID];  // 30 KB
  const int tid = threadIdx.x;
  const int w = tid >> 6, lane = tid & 63;

  // ---- phase 1: S = SCALE * kp @ qp^T (MFMA); wave3 stages qt_old ----
  {
    const int r = lane & 15, kq = lane >> 4;
    const ushort_t* kpb = kp + (size_t)b * NK * HID;
    const ushort_t* qpb = qp + (size_t)b * NQ * HID;
    if (w == 3) {
      const uint4* src = (const uint4*)(qtb_old + (size_t)b * NQ * HID);
      uint4* dst = (uint4*)qts;
#pragma unroll
      for (int it = 0; it < 30; ++it) dst[it * 64 + lane] = src[it * 64 + lane];
    }
    const int rowA = w * 16 + r;
    const int rowB = 64 + w * 16 + r;
    const int rowB_c = rowB < NK ? rowB : NK - 1;
    const int qr1 = (16 + r) < NQ ? (16 + r) : NQ - 1;
    const bool hasB = (w < 3);
    f32x4 aA0 = {0.f, 0.f, 0.f, 0.f}, aA1 = {0.f, 0.f, 0.f, 0.f};
    f32x4 aB0 = {0.f, 0.f, 0.f, 0.f}, aB1 = {0.f, 0.f, 0.f, 0.f};
    for (int k0 = 0; k0 < HID; k0 += 32) {
      bf16x8 b0 = *(const bf16x8*)(qpb + (size_t)r * HID + k0 + kq * 8);
      bf16x8 b1 = *(const bf16x8*)(qpb + (size_t)qr1 * HID + k0 + kq * 8);
      bf16x8 afA = *(const bf16x8*)(kpb + (size_t)rowA * HID + k0 + kq * 8);
      aA0 = __builtin_amdgcn_mfma_f32_16x16x32_bf16(afA, b0, aA0, 0, 0, 0);
      aA1 = __builtin_amdgcn_mfma_f32_16x16x32_bf16(afA, b1, aA1, 0, 0, 0);
      if (hasB) {
        bf16x8 afB = *(const bf16x8*)(kpb + (size_t)rowB_c * HID + k0 + kq * 8);
        aB0 = __builtin_amdgcn_mfma_f32_16x16x32_bf16(afB, b0, aB0, 0, 0, 0);
        aB1 = __builtin_amdgcn_mfma_f32_16x16x32_bf16(afB, b1, aB1, 0, 0, 0);
      }
    }
    const int q0 = lane & 15, mb = (lane >> 4) * 4;
#pragma unroll
    for (int rr = 0; rr < 4; ++rr) {
      const int mA = w * 16 + mb + rr;
      S_lds[mA][q0] = aA0[rr] * SCALE;
      if (q0 + 16 < NQ) S_lds[mA][q0 + 16] = aA1[rr] * SCALE;
      if (hasB) {
        const int mB = 64 + w * 16 + mb + rr;
        if (mB < NK) {
          S_lds[mB][q0] = aB0[rr] * SCALE;
          if (q0 + 16 < NQ) S_lds[mB][q0 + 16] = aB1[rr] * SCALE;
        }
      }
    }
  }
  __syncthreads();
  // ---- phase 2a: Pq (softmax over kr per q) ----
  if (tid < NQ) {
    const int q = tid;
    float m = -1e30f;
    for (int kr = 0; kr < NK; ++kr) m = fmaxf(m, S_lds[kr][q]);
    float s = 0.f;
    for (int kr = 0; kr < NK; ++kr) {
      float e = expf(S_lds[kr][q] - m);
      Pq[q][kr] = e;
      s += e;
    }
    float inv = 1.f / s;
    for (int kr = 0; kr < NK; ++kr) Pq[q][kr] *= inv;
  }
  __syncthreads();
  // ---- phase 2b: Pk in place ----
  if (tid < NK) {
    const int kr = tid;
    float m = -1e30f;
#pragma unroll
    for (int q = 0; q < NQ; ++q) m = fmaxf(m, S_lds[kr][q]);
    float s = 0.f;
    float e[NQ];
#pragma unroll
    for (int q = 0; q < NQ; ++q) {
      e[q] = expf(S_lds[kr][q] - m);
      s += e[q];
    }
    float inv = 1.f / s;
#pragma unroll
    for (int q = 0; q < NQ; ++q) S_lds[kr][q] = e[q] * inv;
  }
  __syncthreads();
  // ---- fused phase 3+4 ----
  const int c2 = tid;  // float2 column index
  float qx[NQ], qy[NQ], ax[NQ], ay[NQ];
#pragma unroll
  for (int q = 0; q < NQ; ++q) {
    unsigned int u = *(const unsigned int*)(qts + q * HID + c2 * 2);
    qx[q] = bf2f((unsigned short)(u & 0xFFFFu));
    qy[q] = bf2f((unsigned short)(u >> 16));
    ax[q] = 0.f;
    ay[q] = 0.f;
  }
  float* xk = Xk + (size_t)b * NK * HID;
  ushort_t* xkb = Xkb + (size_t)b * NK * HID;
  for (int kr = 0; kr < NK; ++kr) {
    const size_t off = (size_t)kr * HID + c2 * 2;
    float2 kv = *(const float2*)(xk + off);
    float sx = kv.x, sy = kv.y;
#pragma unroll
    for (int q = 0; q < NQ; ++q) {
      float pq = Pq[q][kr];
      ax[q] = fmaf(pq, kv.x, ax[q]);
      ay[q] = fmaf(pq, kv.y, ay[q]);
      float pk = S_lds[kr][q];
      sx = fmaf(pk, qx[q], sx);
      sy = fmaf(pk, qy[q], sy);
    }
    *(float2*)(xk + off) = make_float2(sx, sy);
    *(ushort2*)(xkb + off) = make_ushort2(f2bf(sx), f2bf(sy));
  }
#pragma unroll
  for (int q = 0; q < NQ; ++q) {
    const size_t off = ((size_t)b * NQ + q) * HID + c2 * 2;
    float2 res = *(const float2*)(Xq_old + off);
    float ox = ax[q] + res.x, oy = ay[q] + res.y;
    *(float2*)(Xq_new + off) = make_float2(ox, oy);
    *(ushort2*)(qtb_new + off) = make_ushort2(f2bf(ox), f2bf(oy));
  }
}

// ---------------- fused boundary: expproj(rows) -> mean -> logmap -> bf16 ----
// one block per batch; thread owns float2 columns (2t, 2t+1) of the 512-wide rows
__global__ __launch_bounds__(256) void finale_k(
    const float* __restrict__ Xk, const float* __restrict__ Xq,
    ushort_t* __restrict__ lastb, const float* __restrict__ curv) {
  const int b = blockIdx.x, tid = threadIdx.x;
  const float c = curv[NLAYERS];
  const float Kc = 1.f / c, sqrtK = sqrtf(Kc);
  float2 mk = make_float2(0.f, 0.f), mq = make_float2(0.f, 0.f);

  const float* xkp = Xk + (size_t)b * NK * HID;
  for (int r = 0; r < NK; r += 2) {
    float2 xa = *(const float2*)(xkp + (size_t)r * HID + tid * 2);
    float2 xb = *(const float2*)(xkp + (size_t)(r + 1) * HID + tid * 2);
    float2 ssp;
    ssp.x = (tid == 0) ? xa.y * xa.y : (xa.x * xa.x + xa.y * xa.y);
    ssp.y = (tid == 0) ? xb.y * xb.y : (xb.x * xb.x + xb.y * xb.y);
    ssp = blockReduceSum256x2(ssp);
    {
      float n = fmaxf(sqrtf(ssp.x), 1e-15f);
      float f = sqrtK * sinhf(n / sqrtK) / n;
      float first = sqrtf(fmaxf(Kc + f * f * ssp.x, 1e-7f));
      mk.x += (tid == 0) ? first : f * xa.x;
      mk.y += f * xa.y;
    }
    {
      float n = fmaxf(sqrtf(ssp.y), 1e-15f);
      float f = sqrtK * sinhf(n / sqrtK) / n;
      float first = sqrtf(fmaxf(Kc + f * f * ssp.y, 1e-7f));
      mk.x += (tid == 0) ? first : f * xb.x;
      mk.y += f * xb.y;
    }
  }
  const float* xqp = Xq + (size_t)b * NQ * HID;
  for (int r = 0; r < NQ; r += 2) {
    float2 xa = *(const float2*)(xqp + (size_t)r * HID + tid * 2);
    float2 xb = *(const float2*)(xqp + (size_t)(r + 1) * HID + tid * 2);
    float2 ssp;
    ssp.x = (tid == 0) ? xa.y * xa.y : (xa.x * xa.x + xa.y * xa.y);
    ssp.y = (tid == 0) ? xb.y * xb.y : (xb.x * xb.x + xb.y * xb.y);
    ssp = blockReduceSum256x2(ssp);
    {
      float n = fmaxf(sqrtf(ssp.x), 1e-15f);
      float f = sqrtK * sinhf(n / sqrtK) / n;
      float first = sqrtf(fmaxf(Kc + f * f * ssp.x, 1e-7f));
      mq.x += (tid == 0) ? first : f * xa.x;
      mq.y += f * xa.y;
    }
    {
      float n = fmaxf(sqrtf(ssp.y), 1e-15f);
      float f = sqrtK * sinhf(n / sqrtK) / n;
      float first = sqrtf(fmaxf(Kc + f * f * ssp.y, 1e-7f));
      mq.x += (tid == 0) ? first : f * xb.x;
      mq.y += f * xb.y;
    }
  }
  mk.x *= (1.f / NK); mk.y *= (1.f / NK);
  mq.x *= (1.f / NQ); mq.y *= (1.f / NQ);

  // logmap0 on the 1024 concat [mk(512) | mq(512)]; element 0 is time comp
  float2 sq;
  sq.x = ((tid == 0) ? 0.f : mk.x * mk.x) + mk.y * mk.y;
  sq.y = mq.x * mq.x + mq.y * mq.y;
  float2 t2 = blockReduceSum256x2(sq);
  const float ssall = t2.x + t2.y;
  __shared__ float x0sh;
  if (tid == 0) x0sh = mk.x;
  __syncthreads();
  const float x0 = x0sh;
  const float n = fmaxf(sqrtf(ssall), 1e-15f);
  const float theta = fmaxf(x0 / sqrtK, 1.f + 1e-7f);
  const float rr = sqrtK * acoshf(theta) / n;
  ushort_t* ob = lastb + (size_t)b * 1024;
  ushort2 ok = make_ushort2(f2bf(rr * mk.x), f2bf(rr * mk.y));
  if (tid == 0) ok.x = 0;
  *(ushort2*)(ob + tid * 2) = ok;
  *(ushort2*)(ob + 512 + tid * 2) =
      make_ushort2(f2bf(rr * mq.x), f2bf(rr * mq.y));
}

// ---------------- tail ----------------
__global__ __launch_bounds__(512) void logsoftmax_k(float* __restrict__ x) {
  const int b = blockIdx.x, tid = threadIdx.x;
  float4* row = (float4*)(x + (size_t)b * NANS);
  float m = -3.4e38f;
  for (int i = tid; i < NANS / 4; i += 512) {
    float4 v = row[i];
    m = fmaxf(fmaxf(fmaxf(m, v.x), v.y), fmaxf(v.z, v.w));
  }
  m = blockReduceMax512(m);
  float s = 0.f;
  for (int i = tid; i < NANS / 4; i += 512) {
    float4 v = row[i];
    s += expf(v.x - m) + expf(v.y - m) + expf(v.z - m) + expf(v.w - m);
  }
  s = blockReduceSum512(s);
  float lse = m + logf(s);
  for (int i = tid; i < NANS / 4; i += 512) {
    float4 v = row[i];
    v.x -= lse; v.y -= lse; v.z -= lse; v.w -= lse;
    row[i] = v;
  }
}

// ---------------- launch ----------------
extern "C" void kernel_launch(void* const* d_in, const int* in_sizes, int n_in,
                              void* d_out, int out_size, void* d_ws, size_t ws_size,
                              hipStream_t stream) {
  const int* qid = (const int*)d_in[0];
  const int* kid = (const int*)d_in[1];
  const float* emb = (const float*)d_in[2];
  const float* q2h_w = (const float*)d_in[3];
  const float* q2h_b = (const float*)d_in[4];
  const float* k2h_w = (const float*)d_in[5];
  const float* k2h_b = (const float*)d_in[6];
  const float* Wk = (const float*)d_in[7];
  const float* Wq = (const float*)d_in[8];
  const float* curv = (const float*)d_in[9];
  const float* p1w = (const float*)d_in[10];
  const float* p1b = (const float*)d_in[11];
  const float* p2w = (const float*)d_in[12];
  const float* p2b = (const float*)d_in[13];
  const float* glove = (const float*)d_in[14];
  float* out = (float*)d_out;

  // ---- workspace layout ----
  float* f = (float*)d_ws;
  float* Xk = f;                               // 25600*512 (kt, in-place)
  float* Xq0 = Xk + (size_t)MKT * HID;         // 7680*512 (qt ping)
  float* Xq1 = Xq0 + (size_t)MQT * HID;        // 7680*512 (qt pong)
  float* fend = Xq1 + (size_t)MQT * HID;

  ushort_t* u = (ushort_t*)fend;
  ushort_t* Xkb = u;                           // 25600*512 (kt bf16, in-place)
  ushort_t* kpb = Xkb + (size_t)MKT * HID;     // 25600*512 (kp scratch)
  ushort_t* qb0 = kpb + (size_t)MKT * HID;     // 7680*512 (qt bf16 ping)
  ushort_t* qb1 = qb0 + (size_t)MQT * HID;     // 7680*512 (qp / qt bf16 pong)
  ushort_t* q2h_wt = qb1 + (size_t)MQT * HID;  // 512*928
  ushort_t* k2h_wt = q2h_wt + (size_t)HID * KP;
  ushort_t* Wkt = k2h_wt + (size_t)HID * KP;   // 3*512*512
  ushort_t* Wqt = Wkt + (size_t)NLAYERS * HID * HID;
  ushort_t* p1wt = Wqt + (size_t)NLAYERS * HID * HID;   // 512*1024
  ushort_t* p2wt = p1wt + (size_t)HID * 1024;           // 384*512
  ushort_t* lastb = p2wt + (size_t)NOUTP * HID;         // 256*1024
  ushort_t* h1b = lastb + (size_t)BATCH * 1024;         // 256*512
  ushort_t* o2b = h1b + (size_t)BATCH * HID;            // 256*384
  ushort_t* gloveb = o2b + (size_t)BATCH * NOUTP;       // 32000*384

  // ---- weight pre-casts ----
  tcast10_k<<<dim3(16, 32, 10), 256, 0, stream>>>(
      q2h_w, k2h_w, Wk, Wq, p1w, p2w, q2h_wt, k2h_wt, Wkt, Wqt, p1wt, p2wt);

  // ---- input projections with FUSED embedding gather; fused proj_tan0 ----
  mfma_gemm2<1, 1, 1, 1, 1, 0><<<dim3(HID / 128, MQT / 128 + MKT / 128), 256, 0, stream>>>(
      nullptr, qid, q2h_wt, q2h_b, Xq0, qb0, MQT / 128,
      nullptr, kid, k2h_wt, k2h_b, Xk, Xkb, emb, HID, KP, HID);

  // ---- layers in tangent space ----
  float* Xq_cur = Xq0;
  float* Xq_alt = Xq1;
  ushort_t* Xqb_cur = qb0;
  ushort_t* Xqb_alt = qb1;
  for (int i = 0; i < NLAYERS; ++i) {
    mfma_gemm2<0, 0, 0, 1, 0, 0><<<dim3(HID / 128, MKT / 128 + MQT / 128), 256, 0, stream>>>(
        Xkb, nullptr, Wkt + (size_t)i * HID * HID, nullptr, nullptr, kpb, MKT / 128,
        Xqb_cur, nullptr, Wqt + (size_t)i * HID * HID, nullptr, nullptr, Xqb_alt,
        nullptr, HID, HID, HID);
    att_fused_k<<<BATCH, 256, 0, stream>>>(
        kpb, Xqb_alt, Xqb_cur, Xq_cur, Xq_alt, Xqb_alt, Xk, Xkb);
    float* tf = Xq_cur; Xq_cur = Xq_alt; Xq_alt = tf;
    ushort_t* tu = Xqb_cur; Xqb_cur = Xqb_alt; Xqb_alt = tu;
  }

  // ---- fused boundary (expproj + mean + logmap) -> lastb bf16 ----
  finale_k<<<BATCH, 256, 0, stream>>>(Xk, Xq_cur, lastb, curv);

  // glove cast (just before the head that consumes it)
  cast_pad_rows_k<<<NANS, 128, 0, stream>>>(glove, gloveb, NOUT, NOUTP);

  // ---- head (all MFMA bf16) ----
  mfma_gemm2<0, 1, 0, 1, 0, 1><<<dim3(HID / 128, BATCH / 128), 256, 0, stream>>>(
      lastb, nullptr, p1wt, p1b, nullptr, h1b, BATCH / 128,
      lastb, nullptr, p1wt, p1b, nullptr, h1b, nullptr, HID, 1024, HID);
  mfma_gemm2<0, 1, 0, 1, 0, 0><<<dim3(NOUTP / 128, BATCH / 128), 256, 0, stream>>>(
      h1b, nullptr, p2wt, p2b, nullptr, o2b, BATCH / 128,
      h1b, nullptr, p2wt, p2b, nullptr, o2b, nullptr, NOUTP, HID, NOUT);
  mfma_gemm2<0, 0, 1, 0, 0, 0><<<dim3(NANS / 128, BATCH / 128), 256, 0, stream>>>(
      o2b, nullptr, gloveb, nullptr, out, nullptr, BATCH / 128,
      o2b, nullptr, gloveb, nullptr, out, nullptr, nullptr, NANS, NOUTP, NANS);
  logsoftmax_k<<<BATCH, 512, 0, stream>>>(out);
}

// Round 8
// 650.422 us; speedup vs baseline: 1.1582x; 1.1582x over previous
//
#include <hip/hip_runtime.h>
#include <math.h>

// Problem constants (from setup_inputs)
#define BATCH 256
#define NQ 30
#define NK 100
#define HID 512
#define WORD 300
#define KIN 900          // WORD*3
#define KP 928           // KIN padded to multiple of 32
#define NANS 32000
#define NOUT 300
#define NOUTP 384        // NOUT padded to multiple of 128 (MFMA N-tile)
#define NLAYERS 3
#define MQT (BATCH * NQ)   // 7680
#define MKT (BATCH * NK)   // 25600
#define SCALE 0.044194173824159216f  // 1/sqrt(512)

typedef __attribute__((ext_vector_type(8))) short bf16x8;
typedef __attribute__((ext_vector_type(4))) float f32x4;
typedef unsigned short ushort_t;

__device__ __forceinline__ unsigned short f2bf(float f) {
  unsigned int u = __float_as_uint(f);
  u = (u + 0x7FFF + ((u >> 16) & 1)) >> 16;  // RNE
  return (unsigned short)u;
}
__device__ __forceinline__ float bf2f(unsigned short s) {
  return __uint_as_float(((unsigned int)s) << 16);
}

typedef const __attribute__((address_space(1))) unsigned int* gas_u32;
typedef __attribute__((address_space(3))) unsigned int* las_u32;
__device__ __forceinline__ void gld_lds16(const void* g, void* l) {
  __builtin_amdgcn_global_load_lds((gas_u32)g, (las_u32)l, 16, 0, 0);
}

// bijective XCD swizzle (m204)
__device__ __forceinline__ int xcd_swz_linear() {
  const int nwg = gridDim.x * gridDim.y;
  const int orig = blockIdx.y * gridDim.x + blockIdx.x;
  const int q = nwg >> 3, r = nwg & 7;
  const int xcd = orig & 7, idx = orig >> 3;
  return (xcd < r ? xcd * (q + 1) : r * (q + 1) + (xcd - r) * q) + idx;
}

// ---------------- reduction helpers ----------------
__device__ __forceinline__ float waveReduceSum(float v) {
#pragma unroll
  for (int o = 32; o > 0; o >>= 1) v += __shfl_xor(v, o);
  return v;
}
__device__ __forceinline__ float waveReduceMax(float v) {
#pragma unroll
  for (int o = 32; o > 0; o >>= 1) v = fmaxf(v, __shfl_xor(v, o));
  return v;
}
__device__ __forceinline__ float2 waveReduceSum2(float2 v) {
#pragma unroll
  for (int o = 32; o > 0; o >>= 1) {
    v.x += __shfl_xor(v.x, o);
    v.y += __shfl_xor(v.y, o);
  }
  return v;
}
__device__ float2 blockReduceSum256x2(float2 v) {
  __shared__ float2 sm2[4];
  int lane = threadIdx.x & 63, w = threadIdx.x >> 6;
  v = waveReduceSum2(v);
  if (lane == 0) sm2[w] = v;
  __syncthreads();
  float2 r;
  r.x = sm2[0].x + sm2[1].x + sm2[2].x + sm2[3].x;
  r.y = sm2[0].y + sm2[1].y + sm2[2].y + sm2[3].y;
  __syncthreads();
  return r;
}
__device__ float blockReduceSum512(float v) {
  __shared__ float sm[8];
  int lane = threadIdx.x & 63, w = threadIdx.x >> 6;
  v = waveReduceSum(v);
  if (lane == 0) sm[w] = v;
  __syncthreads();
  float r = 0.f;
#pragma unroll
  for (int i = 0; i < 8; ++i) r += sm[i];
  __syncthreads();
  return r;
}
__device__ float blockReduceMax512(float v) {
  __shared__ float sm[8];
  int lane = threadIdx.x & 63, w = threadIdx.x >> 6;
  v = waveReduceMax(v);
  if (lane == 0) sm[w] = v;
  __syncthreads();
  float r = -3.4e38f;
#pragma unroll
  for (int i = 0; i < 8; ++i) r = fmaxf(r, sm[i]);
  __syncthreads();
  return r;
}

// cast 8 f32 from a glove row (length NOUT, zero-pad beyond) to bf16x8
__device__ __forceinline__ bf16x8 castrow8(const float* __restrict__ rowp, int kb) {
  union { ushort_t u[8]; bf16x8 v; } pk;
  if (kb + 8 <= NOUT) {
    // element offset = 300*row + kb : even -> 8B aligned float2 loads
    float2 a0 = *(const float2*)(rowp + kb);
    float2 a1 = *(const float2*)(rowp + kb + 2);
    float2 a2 = *(const float2*)(rowp + kb + 4);
    float2 a3 = *(const float2*)(rowp + kb + 6);
    pk.u[0] = f2bf(a0.x); pk.u[1] = f2bf(a0.y);
    pk.u[2] = f2bf(a1.x); pk.u[3] = f2bf(a1.y);
    pk.u[4] = f2bf(a2.x); pk.u[5] = f2bf(a2.y);
    pk.u[6] = f2bf(a3.x); pk.u[7] = f2bf(a3.y);
  } else {
#pragma unroll
    for (int j = 0; j < 8; ++j) {
      const int kk = kb + j;
      pk.u[j] = (kk < NOUT) ? f2bf(rowp[kk]) : (ushort_t)0;
    }
  }
  return pk.v;
}

// ---------------- bf16 MFMA GEMM (dual operand-set, XCD-swizzled) ----------
// For by < M1b: set1; else set2 rebased. C = A @ Bt^T (+bias[clamped at nbias]).
// BF32B: B is the f32 glove matrix [N][NOUT], cast+pad during staging.
// ZC0: zero col 0 (fused proj_tan0). RELU: epilogue relu.
template <int BF32B, int BIAS, int OUTF32, int OUTBF16, int ZC0, int RELU>
__global__ __launch_bounds__(256) void mfma_gemm2(
    const ushort_t* __restrict__ A1, const ushort_t* __restrict__ Bt1,
    const float* __restrict__ bias1, float* __restrict__ C1,
    ushort_t* __restrict__ Cb1, int M1b,
    const ushort_t* __restrict__ A2, const ushort_t* __restrict__ Bt2,
    const float* __restrict__ bias2, float* __restrict__ C2,
    ushort_t* __restrict__ Cb2, const float* __restrict__ Bf,
    int N, int K, int nbias) {
  __shared__ __align__(16) ushort_t Abuf[128 * 32];
  __shared__ __align__(16) ushort_t Bbuf[128 * 32];
  const int wg = xcd_swz_linear();
  const int bx = wg % gridDim.x, by = wg / gridDim.x;
  const bool sel = (by >= M1b);
  const ushort_t* A = sel ? A2 : A1;
  const ushort_t* Bt = sel ? Bt2 : Bt1;
  const float* bias = sel ? bias2 : bias1;
  float* C = sel ? C2 : C1;
  ushort_t* Cb = sel ? Cb2 : Cb1;
  const int row0 = (sel ? (by - M1b) : by) * 128;
  const int col0 = bx * 128;

  const int tid = threadIdx.x;
  const int lane = tid & 63, w = tid >> 6;
  const int wr = w >> 1, wc = w & 1;
  const int s_r = lane & 15, s_kq = lane >> 4;

  const size_t a_src0 = (size_t)(row0 + (w * 2 + 0) * 16 + s_r) * K + s_kq * 8;
  const size_t a_src1 = (size_t)(row0 + (w * 2 + 1) * 16 + s_r) * K + s_kq * 8;
  const size_t b_src0 = (size_t)(col0 + (w * 2 + 0) * 16 + s_r) * K + s_kq * 8;
  const size_t b_src1 = (size_t)(col0 + (w * 2 + 1) * 16 + s_r) * K + s_kq * 8;
  ushort_t* a_dst0 = Abuf + (w * 2 + 0) * 512;
  ushort_t* a_dst1 = Abuf + (w * 2 + 1) * 512;
  ushort_t* b_dst0 = Bbuf + (w * 2 + 0) * 512;
  ushort_t* b_dst1 = Bbuf + (w * 2 + 1) * 512;
  const float* bf_row0 = BF32B ? (Bf + (size_t)(col0 + (w * 2 + 0) * 16 + s_r) * NOUT) : nullptr;
  const float* bf_row1 = BF32B ? (Bf + (size_t)(col0 + (w * 2 + 1) * 16 + s_r) * NOUT) : nullptr;

  f32x4 acc[4][4];
#pragma unroll
  for (int i = 0; i < 4; ++i)
#pragma unroll
    for (int j = 0; j < 4; ++j) acc[i][j] = (f32x4){0.f, 0.f, 0.f, 0.f};

  for (int k0 = 0; k0 < K; k0 += 32) {
    gld_lds16(A + a_src0 + k0, a_dst0);
    gld_lds16(A + a_src1 + k0, a_dst1);
    if (BF32B) {
      const int kb = k0 + s_kq * 8;
      *(bf16x8*)(b_dst0 + lane * 8) = castrow8(bf_row0, kb);
      *(bf16x8*)(b_dst1 + lane * 8) = castrow8(bf_row1, kb);
    } else {
      gld_lds16(Bt + b_src0 + k0, b_dst0);
      gld_lds16(Bt + b_src1 + k0, b_dst1);
    }
    __syncthreads();
    bf16x8 af[4], bfr[4];
#pragma unroll
    for (int mi = 0; mi < 4; ++mi)
      af[mi] = *(const bf16x8*)(Abuf + (wr * 4 + mi) * 512 + lane * 8);
#pragma unroll
    for (int nj = 0; nj < 4; ++nj)
      bfr[nj] = *(const bf16x8*)(Bbuf + (wc * 4 + nj) * 512 + lane * 8);
#pragma unroll
    for (int mi = 0; mi < 4; ++mi)
#pragma unroll
      for (int nj = 0; nj < 4; ++nj)
        acc[mi][nj] = __builtin_amdgcn_mfma_f32_16x16x32_bf16(
            af[mi], bfr[nj], acc[mi][nj], 0, 0, 0);
    __syncthreads();
  }

#pragma unroll
  for (int nj = 0; nj < 4; ++nj) {
    const int n = col0 + wc * 64 + nj * 16 + (lane & 15);
    const float bb = BIAS ? ((n < nbias) ? bias[n] : 0.f) : 0.f;
#pragma unroll
    for (int mi = 0; mi < 4; ++mi) {
      f32x4 v = acc[mi][nj];
#pragma unroll
      for (int r = 0; r < 4; ++r) {
        const int m = row0 + wr * 64 + mi * 16 + (lane >> 4) * 4 + r;
        float val = v[r] + bb;
        if (RELU) val = fmaxf(val, 0.f);
        if (ZC0 && n == 0) val = 0.f;
        if (OUTF32) C[(size_t)m * N + n] = val;
        if (OUTBF16) Cb[(size_t)m * N + n] = f2bf(val);
      }
    }
  }
}

// ---------------- pre-cast kernels ----------------
// merged gather: blocks [0,MQT) -> gq, [MQT, MQT+MKT) -> gk
__global__ __launch_bounds__(256) void gather_all_k(
    const int* __restrict__ qid, const int* __restrict__ kid,
    const float* __restrict__ emb, ushort_t* __restrict__ gq,
    ushort_t* __restrict__ gk) {
  int m = blockIdx.x;
  const int* ids;
  ushort_t* outp;
  if (m < MQT) {
    ids = qid + m * 3;
    outp = gq + (size_t)m * KP;
  } else {
    m -= MQT;
    ids = kid + m * 3;
    outp = gk + (size_t)m * KP;
  }
  const int t = threadIdx.x;
  if (t >= KP / 4) return;
  const int k = t * 4;
  ushort4 o = make_ushort4(0, 0, 0, 0);
  if (k < KIN) {
    const int node = (k >= 600) ? 2 : ((k >= 300) ? 1 : 0);
    const int off = k - node * 300;
    const int id = ids[node];
    float4 v = *(const float4*)(emb + (size_t)id * 300 + off);
    if (v.x != v.x) v.x = 0.f;
    if (v.y != v.y) v.y = 0.f;
    if (v.z != v.z) v.z = 0.f;
    if (v.w != v.w) v.w = 0.f;
    o = make_ushort4(f2bf(v.x), f2bf(v.y), f2bf(v.z), f2bf(v.w));
  }
  *(ushort4*)(outp + k) = o;
}

// merged transpose-cast, 10 jobs:
// z=0 q2h, z=1 k2h, z=2..4 Wk[i], z=5..7 Wq[i], z=8 p1w, z=9 p2w
__global__ __launch_bounds__(256) void tcast10_k(
    const float* __restrict__ q2h_w, const float* __restrict__ k2h_w,
    const float* __restrict__ Wk, const float* __restrict__ Wq,
    const float* __restrict__ p1w, const float* __restrict__ p2w,
    ushort_t* __restrict__ q2h_wt, ushort_t* __restrict__ k2h_wt,
    ushort_t* __restrict__ Wkt, ushort_t* __restrict__ Wqt,
    ushort_t* __restrict__ p1wt, ushort_t* __restrict__ p2wt) {
  const int z = blockIdx.z;
  const float* src;
  ushort_t* dst;
  int R, Cc, Rp, Cp;
  if (z == 0)      { src = q2h_w; dst = q2h_wt; R = KIN;  Cc = HID;  Rp = KP;   Cp = HID; }
  else if (z == 1) { src = k2h_w; dst = k2h_wt; R = KIN;  Cc = HID;  Rp = KP;   Cp = HID; }
  else if (z < 5)  { int i = z - 2; src = Wk + (size_t)i * HID * HID; dst = Wkt + (size_t)i * HID * HID; R = HID; Cc = HID; Rp = HID; Cp = HID; }
  else if (z < 8)  { int i = z - 5; src = Wq + (size_t)i * HID * HID; dst = Wqt + (size_t)i * HID * HID; R = HID; Cc = HID; Rp = HID; Cp = HID; }
  else if (z == 8) { src = p1w; dst = p1wt; R = 1024; Cc = HID;  Rp = 1024; Cp = HID; }
  else             { src = p2w; dst = p2wt; R = HID;  Cc = NOUT; Rp = HID;  Cp = NOUTP; }
  const int r0 = blockIdx.y * 32, c0 = blockIdx.x * 32;
  if (r0 >= Rp || c0 >= Cp) return;
  __shared__ float t[32][33];
  const int tx = threadIdx.x & 31, ty = threadIdx.x >> 5;
#pragma unroll
  for (int i = 0; i < 4; ++i) {
    int r = r0 + ty + i * 8, c = c0 + tx;
    t[ty + i * 8][tx] = (r < R && c < Cc) ? src[(size_t)r * Cc + c] : 0.f;
  }
  __syncthreads();
#pragma unroll
  for (int i = 0; i < 4; ++i) {
    int c = c0 + ty + i * 8, r = r0 + tx;
    if (c < Cp && r < Rp) dst[(size_t)c * Rp + r] = f2bf(t[tx][ty + i * 8]);
  }
}

// ---------------- fused attention, bf16 state, 512 threads ----------------
// State ping-pong: kt_old in Ktc, kp in Kta (from GEMM); att writes kt_new
// over kp in Kta. qp in Qba (from GEMM); qt_old in Qbc; att writes qt_new
// over qp in Qba.
// phase1 (waves 0-6): S = SCALE*kp@qp^T via MFMA -> LDS; wave7 stages qt_old
// phase2a/2b: softmaxes; phase3 (waves 0-3): att_q; phase4 (waves 4-7): att_k
__global__ __launch_bounds__(512) void att_fused_k(
    const ushort_t* __restrict__ Kta, const ushort_t* __restrict__ Qba,
    const ushort_t* __restrict__ Qbc, const ushort_t* __restrict__ Ktc,
    ushort_t* __restrict__ KtaW, ushort_t* __restrict__ QbaW) {
  const int b = blockIdx.x;
  __shared__ float S_lds[NK][33];        // scores -> Pk in place (13.2 KB)
  __shared__ float Pq[NQ][NK + 4];       // 12.5 KB
  __shared__ __align__(16) ushort_t qts[NQ * HID];  // 30 KB
  const int tid = threadIdx.x;
  const int w = tid >> 6, lane = tid & 63;

  // ---- phase 1 ----
  {
    const int r = lane & 15, kq = lane >> 4;
    const ushort_t* kpb = Kta + (size_t)b * NK * HID;
    const ushort_t* qpb = Qba + (size_t)b * NQ * HID;
    if (w == 7) {
      const uint4* src = (const uint4*)(Qbc + (size_t)b * NQ * HID);
      uint4* dst = (uint4*)qts;
#pragma unroll
      for (int it = 0; it < 30; ++it) dst[it * 64 + lane] = src[it * 64 + lane];
    } else {
      const int rowA = w * 16 + r;
      const int rowA_c = (rowA < NK) ? rowA : (NK - 1);
      const int qr1 = (16 + r) < NQ ? (16 + r) : NQ - 1;
      f32x4 a0 = {0.f, 0.f, 0.f, 0.f}, a1 = {0.f, 0.f, 0.f, 0.f};
      for (int k0 = 0; k0 < HID; k0 += 32) {
        bf16x8 af = *(const bf16x8*)(kpb + (size_t)rowA_c * HID + k0 + kq * 8);
        bf16x8 b0 = *(const bf16x8*)(qpb + (size_t)r * HID + k0 + kq * 8);
        bf16x8 b1 = *(const bf16x8*)(qpb + (size_t)qr1 * HID + k0 + kq * 8);
        a0 = __builtin_amdgcn_mfma_f32_16x16x32_bf16(af, b0, a0, 0, 0, 0);
        a1 = __builtin_amdgcn_mfma_f32_16x16x32_bf16(af, b1, a1, 0, 0, 0);
      }
      const int q0 = lane & 15, mb = (lane >> 4) * 4;
#pragma unroll
      for (int rr = 0; rr < 4; ++rr) {
        const int mA = w * 16 + mb + rr;
        if (mA < NK) {
          S_lds[mA][q0] = a0[rr] * SCALE;
          if (q0 + 16 < NQ) S_lds[mA][q0 + 16] = a1[rr] * SCALE;
        }
      }
    }
  }
  __syncthreads();
  // ---- phase 2a: Pq (softmax over kr per q) ----
  if (tid < NQ) {
    const int q = tid;
    float m = -1e30f;
    for (int kr = 0; kr < NK; ++kr) m = fmaxf(m, S_lds[kr][q]);
    float s = 0.f;
    for (int kr = 0; kr < NK; ++kr) {
      float e = expf(S_lds[kr][q] - m);
      Pq[q][kr] = e;
      s += e;
    }
    float inv = 1.f / s;
    for (int kr = 0; kr < NK; ++kr) Pq[q][kr] *= inv;
  }
  __syncthreads();
  // ---- phase 2b: Pk in place ----
  if (tid < NK) {
    const int kr = tid;
    float m = -1e30f;
#pragma unroll
    for (int q = 0; q < NQ; ++q) m = fmaxf(m, S_lds[kr][q]);
    float s = 0.f;
    float e[NQ];
#pragma unroll
    for (int q = 0; q < NQ; ++q) {
      e[q] = expf(S_lds[kr][q] - m);
      s += e[q];
    }
    float inv = 1.f / s;
#pragma unroll
    for (int q = 0; q < NQ; ++q) S_lds[kr][q] = e[q] * inv;
  }
  __syncthreads();

  const ushort_t* ktc = Ktc + (size_t)b * NK * HID;
  if (tid < 256) {
    // ---- phase 3 (waves 0-3): att_q = Pq @ kt_old + qt_old ----
    const int c2 = tid;  // float2 column pair
    float ax[NQ], ay[NQ];
#pragma unroll
    for (int q = 0; q < NQ; ++q) { ax[q] = 0.f; ay[q] = 0.f; }
    for (int kr = 0; kr < NK; ++kr) {
      unsigned int u = *(const unsigned int*)(ktc + (size_t)kr * HID + c2 * 2);
      float kx = bf2f((unsigned short)(u & 0xFFFFu));
      float ky = bf2f((unsigned short)(u >> 16));
#pragma unroll
      for (int q = 0; q < NQ; ++q) {
        float p = Pq[q][kr];
        ax[q] = fmaf(p, kx, ax[q]);
        ay[q] = fmaf(p, ky, ay[q]);
      }
    }
    ushort_t* qout = QbaW + (size_t)b * NQ * HID;
#pragma unroll
    for (int q = 0; q < NQ; ++q) {
      unsigned int u = *(const unsigned int*)(qts + q * HID + c2 * 2);
      float rx = bf2f((unsigned short)(u & 0xFFFFu));
      float ry = bf2f((unsigned short)(u >> 16));
      *(ushort2*)(qout + (size_t)q * HID + c2 * 2) =
          make_ushort2(f2bf(ax[q] + rx), f2bf(ay[q] + ry));
    }
  } else {
    // ---- phase 4 (waves 4-7): att_k = Pk @ qt_old + kt_old ----
    const int c2 = tid - 256;
    float qx[NQ], qy[NQ];
#pragma unroll
    for (int q = 0; q < NQ; ++q) {
      unsigned int u = *(const unsigned int*)(qts + q * HID + c2 * 2);
      qx[q] = bf2f((unsigned short)(u & 0xFFFFu));
      qy[q] = bf2f((unsigned short)(u >> 16));
    }
    ushort_t* kout = KtaW + (size_t)b * NK * HID;
    for (int kr = 0; kr < NK; ++kr) {
      unsigned int u = *(const unsigned int*)(ktc + (size_t)kr * HID + c2 * 2);
      float sx = bf2f((unsigned short)(u & 0xFFFFu));
      float sy = bf2f((unsigned short)(u >> 16));
#pragma unroll
      for (int q = 0; q < NQ; ++q) {
        float p = S_lds[kr][q];
        sx = fmaf(p, qx[q], sx);
        sy = fmaf(p, qy[q], sy);
      }
      *(ushort2*)(kout + (size_t)kr * HID + c2 * 2) =
          make_ushort2(f2bf(sx), f2bf(sy));
    }
  }
}

// ---------------- fused boundary: expproj(rows) -> mean -> logmap -> bf16 ----
// one block per batch; thread owns bf16 column pair (2t, 2t+1); state is bf16
__global__ __launch_bounds__(256) void finale_k(
    const ushort_t* __restrict__ Kb, const ushort_t* __restrict__ Qb,
    ushort_t* __restrict__ lastb, const float* __restrict__ curv) {
  const int b = blockIdx.x, tid = threadIdx.x;
  const float c = curv[NLAYERS];
  const float Kc = 1.f / c, sqrtK = sqrtf(Kc);
  float2 mk = make_float2(0.f, 0.f), mq = make_float2(0.f, 0.f);

  const ushort_t* xkp = Kb + (size_t)b * NK * HID;
  for (int r = 0; r < NK; r += 2) {
    unsigned int ua = *(const unsigned int*)(xkp + (size_t)r * HID + tid * 2);
    unsigned int ub = *(const unsigned int*)(xkp + (size_t)(r + 1) * HID + tid * 2);
    float2 xa = make_float2(bf2f((unsigned short)(ua & 0xFFFFu)),
                            bf2f((unsigned short)(ua >> 16)));
    float2 xb = make_float2(bf2f((unsigned short)(ub & 0xFFFFu)),
                            bf2f((unsigned short)(ub >> 16)));
    float2 ssp;
    ssp.x = (tid == 0) ? xa.y * xa.y : (xa.x * xa.x + xa.y * xa.y);
    ssp.y = (tid == 0) ? xb.y * xb.y : (xb.x * xb.x + xb.y * xb.y);
    ssp = blockReduceSum256x2(ssp);
    {
      float n = fmaxf(sqrtf(ssp.x), 1e-15f);
      float f = sqrtK * sinhf(n / sqrtK) / n;
      float first = sqrtf(fmaxf(Kc + f * f * ssp.x, 1e-7f));
      mk.x += (tid == 0) ? first : f * xa.x;
      mk.y += f * xa.y;
    }
    {
      float n = fmaxf(sqrtf(ssp.y), 1e-15f);
      float f = sqrtK * sinhf(n / sqrtK) / n;
      float first = sqrtf(fmaxf(Kc + f * f * ssp.y, 1e-7f));
      mk.x += (tid == 0) ? first : f * xb.x;
      mk.y += f * xb.y;
    }
  }
  const ushort_t* xqp = Qb + (size_t)b * NQ * HID;
  for (int r = 0; r < NQ; r += 2) {
    unsigned int ua = *(const unsigned int*)(xqp + (size_t)r * HID + tid * 2);
    unsigned int ub = *(const unsigned int*)(xqp + (size_t)(r + 1) * HID + tid * 2);
    float2 xa = make_float2(bf2f((unsigned short)(ua & 0xFFFFu)),
                            bf2f((unsigned short)(ua >> 16)));
    float2 xb = make_float2(bf2f((unsigned short)(ub & 0xFFFFu)),
                            bf2f((unsigned short)(ub >> 16)));
    float2 ssp;
    ssp.x = (tid == 0) ? xa.y * xa.y : (xa.x * xa.x + xa.y * xa.y);
    ssp.y = (tid == 0) ? xb.y * xb.y : (xb.x * xb.x + xb.y * xb.y);
    ssp = blockReduceSum256x2(ssp);
    {
      float n = fmaxf(sqrtf(ssp.x), 1e-15f);
      float f = sqrtK * sinhf(n / sqrtK) / n;
      float first = sqrtf(fmaxf(Kc + f * f * ssp.x, 1e-7f));
      mq.x += (tid == 0) ? first : f * xa.x;
      mq.y += f * xa.y;
    }
    {
      float n = fmaxf(sqrtf(ssp.y), 1e-15f);
      float f = sqrtK * sinhf(n / sqrtK) / n;
      float first = sqrtf(fmaxf(Kc + f * f * ssp.y, 1e-7f));
      mq.x += (tid == 0) ? first : f * xb.x;
      mq.y += f * xb.y;
    }
  }
  mk.x *= (1.f / NK); mk.y *= (1.f / NK);
  mq.x *= (1.f / NQ); mq.y *= (1.f / NQ);

  // logmap0 on the 1024 concat [mk(512) | mq(512)]
  float2 sq;
  sq.x = ((tid == 0) ? 0.f : mk.x * mk.x) + mk.y * mk.y;
  sq.y = mq.x * mq.x + mq.y * mq.y;
  float2 t2 = blockReduceSum256x2(sq);
  const float ssall = t2.x + t2.y;
  __shared__ float x0sh;
  if (tid == 0) x0sh = mk.x;
  __syncthreads();
  const float x0 = x0sh;
  const float n = fmaxf(sqrtf(ssall), 1e-15f);
  const float theta = fmaxf(x0 / sqrtK, 1.f + 1e-7f);
  const float rr = sqrtK * acoshf(theta) / n;
  ushort_t* ob = lastb + (size_t)b * 1024;
  ushort2 ok = make_ushort2(f2bf(rr * mk.x), f2bf(rr * mk.y));
  if (tid == 0) ok.x = 0;
  *(ushort2*)(ob + tid * 2) = ok;
  *(ushort2*)(ob + 512 + tid * 2) =
      make_ushort2(f2bf(rr * mq.x), f2bf(rr * mq.y));
}

// ---------------- tail ----------------
__global__ __launch_bounds__(512) void logsoftmax_k(float* __restrict__ x) {
  const int b = blockIdx.x, tid = threadIdx.x;
  float4* row = (float4*)(x + (size_t)b * NANS);
  float m = -3.4e38f;
  for (int i = tid; i < NANS / 4; i += 512) {
    float4 v = row[i];
    m = fmaxf(fmaxf(fmaxf(m, v.x), v.y), fmaxf(v.z, v.w));
  }
  m = blockReduceMax512(m);
  float s = 0.f;
  for (int i = tid; i < NANS / 4; i += 512) {
    float4 v = row[i];
    s += expf(v.x - m) + expf(v.y - m) + expf(v.z - m) + expf(v.w - m);
  }
  s = blockReduceSum512(s);
  float lse = m + logf(s);
  for (int i = tid; i < NANS / 4; i += 512) {
    float4 v = row[i];
    v.x -= lse; v.y -= lse; v.z -= lse; v.w -= lse;
    row[i] = v;
  }
}

// ---------------- launch ----------------
extern "C" void kernel_launch(void* const* d_in, const int* in_sizes, int n_in,
                              void* d_out, int out_size, void* d_ws, size_t ws_size,
                              hipStream_t stream) {
  const int* qid = (const int*)d_in[0];
  const int* kid = (const int*)d_in[1];
  const float* emb = (const float*)d_in[2];
  const float* q2h_w = (const float*)d_in[3];
  const float* q2h_b = (const float*)d_in[4];
  const float* k2h_w = (const float*)d_in[5];
  const float* k2h_b = (const float*)d_in[6];
  const float* Wk = (const float*)d_in[7];
  const float* Wq = (const float*)d_in[8];
  const float* curv = (const float*)d_in[9];
  const float* p1w = (const float*)d_in[10];
  const float* p1b = (const float*)d_in[11];
  const float* p2w = (const float*)d_in[12];
  const float* p2b = (const float*)d_in[13];
  const float* glove = (const float*)d_in[14];
  float* out = (float*)d_out;

  // ---- workspace layout (all bf16) ----
  ushort_t* u = (ushort_t*)d_ws;
  ushort_t* Kb0 = u;                           // 25600*512 (k-state ping)
  ushort_t* Kb1 = Kb0 + (size_t)MKT * HID;     // 25600*512 (k-state pong / kp)
  ushort_t* qb0 = Kb1 + (size_t)MKT * HID;     // 7680*512 (q-state ping)
  ushort_t* qb1 = qb0 + (size_t)MQT * HID;     // 7680*512 (q-state pong / qp)
  ushort_t* gq = qb1 + (size_t)MQT * HID;      // 7680*928
  ushort_t* gk = gq + (size_t)MQT * KP;        // 25600*928
  ushort_t* q2h_wt = gk + (size_t)MKT * KP;    // 928*512 (stored [N][K])
  ushort_t* k2h_wt = q2h_wt + (size_t)HID * KP;
  ushort_t* Wkt = k2h_wt + (size_t)HID * KP;   // 3*512*512
  ushort_t* Wqt = Wkt + (size_t)NLAYERS * HID * HID;
  ushort_t* p1wt = Wqt + (size_t)NLAYERS * HID * HID;   // 512*1024
  ushort_t* p2wt = p1wt + (size_t)HID * 1024;           // 384*512
  ushort_t* lastb = p2wt + (size_t)NOUTP * HID;         // 256*1024
  ushort_t* h1b = lastb + (size_t)BATCH * 1024;         // 256*512
  ushort_t* o2b = h1b + (size_t)BATCH * HID;            // 256*384

  // ---- pre-casts ----
  gather_all_k<<<MQT + MKT, 256, 0, stream>>>(qid, kid, emb, gq, gk);
  tcast10_k<<<dim3(16, 32, 10), 256, 0, stream>>>(
      q2h_w, k2h_w, Wk, Wq, p1w, p2w, q2h_wt, k2h_wt, Wkt, Wqt, p1wt, p2wt);

  // ---- input projections (merged q+k), fused proj_tan0, bf16 out only ----
  mfma_gemm2<0, 1, 0, 1, 1, 0><<<dim3(HID / 128, MQT / 128 + MKT / 128), 256, 0, stream>>>(
      gq, q2h_wt, q2h_b, nullptr, qb0, MQT / 128,
      gk, k2h_wt, k2h_b, nullptr, Kb0, nullptr, HID, KP, HID);

  // ---- layers in tangent space (bf16 state ping-pong) ----
  ushort_t* Kc = Kb0;  // k-state current
  ushort_t* Ka = Kb1;  // k scratch / next state
  ushort_t* Qc = qb0;
  ushort_t* Qa = qb1;
  for (int i = 0; i < NLAYERS; ++i) {
    // kp = kt@Wk -> Ka ; qp = qt@Wq -> Qa
    mfma_gemm2<0, 0, 0, 1, 0, 0><<<dim3(HID / 128, MKT / 128 + MQT / 128), 256, 0, stream>>>(
        Kc, Wkt + (size_t)i * HID * HID, nullptr, nullptr, Ka, MKT / 128,
        Qc, Wqt + (size_t)i * HID * HID, nullptr, nullptr, Qa,
        nullptr, HID, HID, HID);
    // attention: writes new kt over Ka, new qt over Qa
    att_fused_k<<<BATCH, 512, 0, stream>>>(Ka, Qa, Qc, Kc, Ka, Qa);
    ushort_t* t1 = Kc; Kc = Ka; Ka = t1;
    ushort_t* t2 = Qc; Qc = Qa; Qa = t2;
  }

  // ---- fused boundary (expproj + mean + logmap) -> lastb bf16 ----
  finale_k<<<BATCH, 256, 0, stream>>>(Kc, Qc, lastb, curv);

  // ---- head (all MFMA bf16) ----
  mfma_gemm2<0, 1, 0, 1, 0, 1><<<dim3(HID / 128, BATCH / 128), 256, 0, stream>>>(
      lastb, p1wt, p1b, nullptr, h1b, BATCH / 128,
      lastb, p1wt, p1b, nullptr, h1b, nullptr, HID, 1024, HID);
  mfma_gemm2<0, 1, 0, 1, 0, 0><<<dim3(NOUTP / 128, BATCH / 128), 256, 0, stream>>>(
      h1b, p2wt, p2b, nullptr, o2b, BATCH / 128,
      h1b, p2wt, p2b, nullptr, o2b, nullptr, NOUTP, HID, NOUT);
  // sim: B staged directly from f32 glove (cast in-register)
  mfma_gemm2<1, 0, 1, 0, 0, 0><<<dim3(NANS / 128, BATCH / 128), 256, 0, stream>>>(
      o2b, nullptr, nullptr, out, nullptr, BATCH / 128,
      o2b, nullptr, nullptr, out, nullptr, glove, NANS, NOUTP, NANS);
  logsoftmax_k<<<BATCH, 512, 0, stream>>>(out);
}

// Round 9
// 587.972 us; speedup vs baseline: 1.2812x; 1.1062x over previous
//
#include <hip/hip_runtime.h>
#include <math.h>

// Problem constants (from setup_inputs)
#define BATCH 256
#define NQ 30
#define NK 100
#define HID 512
#define WORD 300
#define KIN 900          // WORD*3
#define KP 928           // KIN padded to multiple of 32
#define NANS 32000
#define NOUT 300
#define NOUTP 384        // NOUT padded to multiple of 128 (MFMA N-tile)
#define NLAYERS 3
#define MQT (BATCH * NQ)   // 7680
#define MKT (BATCH * NK)   // 25600
#define SCALE 0.044194173824159216f  // 1/sqrt(512)

typedef __attribute__((ext_vector_type(8))) short bf16x8;
typedef __attribute__((ext_vector_type(4))) float f32x4;
typedef unsigned short ushort_t;

__device__ __forceinline__ unsigned short f2bf(float f) {
  unsigned int u = __float_as_uint(f);
  u = (u + 0x7FFF + ((u >> 16) & 1)) >> 16;  // RNE
  return (unsigned short)u;
}
__device__ __forceinline__ float bf2f(unsigned short s) {
  return __uint_as_float(((unsigned int)s) << 16);
}

typedef const __attribute__((address_space(1))) unsigned int* gas_u32;
typedef __attribute__((address_space(3))) unsigned int* las_u32;
__device__ __forceinline__ void gld_lds16(const void* g, void* l) {
  __builtin_amdgcn_global_load_lds((gas_u32)g, (las_u32)l, 16, 0, 0);
}

// bijective XCD swizzle (m204)
__device__ __forceinline__ int xcd_swz_linear() {
  const int nwg = gridDim.x * gridDim.y;
  const int orig = blockIdx.y * gridDim.x + blockIdx.x;
  const int q = nwg >> 3, r = nwg & 7;
  const int xcd = orig & 7, idx = orig >> 3;
  return (xcd < r ? xcd * (q + 1) : r * (q + 1) + (xcd - r) * q) + idx;
}

// ---------------- reduction helpers ----------------
__device__ __forceinline__ float waveReduceSum(float v) {
#pragma unroll
  for (int o = 32; o > 0; o >>= 1) v += __shfl_xor(v, o);
  return v;
}
__device__ __forceinline__ float waveReduceMax(float v) {
#pragma unroll
  for (int o = 32; o > 0; o >>= 1) v = fmaxf(v, __shfl_xor(v, o));
  return v;
}
__device__ float blockReduceSum512(float v) {
  __shared__ float sm[8];
  int lane = threadIdx.x & 63, w = threadIdx.x >> 6;
  v = waveReduceSum(v);
  if (lane == 0) sm[w] = v;
  __syncthreads();
  float r = 0.f;
#pragma unroll
  for (int i = 0; i < 8; ++i) r += sm[i];
  __syncthreads();
  return r;
}

// cast 8 f32 from a glove row (length NOUT, zero-pad beyond) to bf16x8
__device__ __forceinline__ bf16x8 castrow8(const float* __restrict__ rowp, int kb) {
  union { ushort_t u[8]; bf16x8 v; } pk;
  if (kb + 8 <= NOUT) {
    float2 a0 = *(const float2*)(rowp + kb);
    float2 a1 = *(const float2*)(rowp + kb + 2);
    float2 a2 = *(const float2*)(rowp + kb + 4);
    float2 a3 = *(const float2*)(rowp + kb + 6);
    pk.u[0] = f2bf(a0.x); pk.u[1] = f2bf(a0.y);
    pk.u[2] = f2bf(a1.x); pk.u[3] = f2bf(a1.y);
    pk.u[4] = f2bf(a2.x); pk.u[5] = f2bf(a2.y);
    pk.u[6] = f2bf(a3.x); pk.u[7] = f2bf(a3.y);
  } else {
#pragma unroll
    for (int j = 0; j < 8; ++j) {
      const int kk = kb + j;
      pk.u[j] = (kk < NOUT) ? f2bf(rowp[kk]) : (ushort_t)0;
    }
  }
  return pk.v;
}

// ---------------- bf16 MFMA GEMM (dual operand-set, XCD-swizzled) ----------
template <int BF32B, int BIAS, int OUTF32, int OUTBF16, int ZC0, int RELU>
__global__ __launch_bounds__(256) void mfma_gemm2(
    const ushort_t* __restrict__ A1, const ushort_t* __restrict__ Bt1,
    const float* __restrict__ bias1, float* __restrict__ C1,
    ushort_t* __restrict__ Cb1, int M1b,
    const ushort_t* __restrict__ A2, const ushort_t* __restrict__ Bt2,
    const float* __restrict__ bias2, float* __restrict__ C2,
    ushort_t* __restrict__ Cb2, const float* __restrict__ Bf,
    int N, int K, int nbias) {
  __shared__ __align__(16) ushort_t Abuf[128 * 32];
  __shared__ __align__(16) ushort_t Bbuf[128 * 32];
  const int wg = xcd_swz_linear();
  const int bx = wg % gridDim.x, by = wg / gridDim.x;
  const bool sel = (by >= M1b);
  const ushort_t* A = sel ? A2 : A1;
  const ushort_t* Bt = sel ? Bt2 : Bt1;
  const float* bias = sel ? bias2 : bias1;
  float* C = sel ? C2 : C1;
  ushort_t* Cb = sel ? Cb2 : Cb1;
  const int row0 = (sel ? (by - M1b) : by) * 128;
  const int col0 = bx * 128;

  const int tid = threadIdx.x;
  const int lane = tid & 63, w = tid >> 6;
  const int wr = w >> 1, wc = w & 1;
  const int s_r = lane & 15, s_kq = lane >> 4;

  const size_t a_src0 = (size_t)(row0 + (w * 2 + 0) * 16 + s_r) * K + s_kq * 8;
  const size_t a_src1 = (size_t)(row0 + (w * 2 + 1) * 16 + s_r) * K + s_kq * 8;
  const size_t b_src0 = (size_t)(col0 + (w * 2 + 0) * 16 + s_r) * K + s_kq * 8;
  const size_t b_src1 = (size_t)(col0 + (w * 2 + 1) * 16 + s_r) * K + s_kq * 8;
  ushort_t* a_dst0 = Abuf + (w * 2 + 0) * 512;
  ushort_t* a_dst1 = Abuf + (w * 2 + 1) * 512;
  ushort_t* b_dst0 = Bbuf + (w * 2 + 0) * 512;
  ushort_t* b_dst1 = Bbuf + (w * 2 + 1) * 512;
  const float* bf_row0 = BF32B ? (Bf + (size_t)(col0 + (w * 2 + 0) * 16 + s_r) * NOUT) : nullptr;
  const float* bf_row1 = BF32B ? (Bf + (size_t)(col0 + (w * 2 + 1) * 16 + s_r) * NOUT) : nullptr;

  f32x4 acc[4][4];
#pragma unroll
  for (int i = 0; i < 4; ++i)
#pragma unroll
    for (int j = 0; j < 4; ++j) acc[i][j] = (f32x4){0.f, 0.f, 0.f, 0.f};

  for (int k0 = 0; k0 < K; k0 += 32) {
    gld_lds16(A + a_src0 + k0, a_dst0);
    gld_lds16(A + a_src1 + k0, a_dst1);
    if (BF32B) {
      const int kb = k0 + s_kq * 8;
      *(bf16x8*)(b_dst0 + lane * 8) = castrow8(bf_row0, kb);
      *(bf16x8*)(b_dst1 + lane * 8) = castrow8(bf_row1, kb);
    } else {
      gld_lds16(Bt + b_src0 + k0, b_dst0);
      gld_lds16(Bt + b_src1 + k0, b_dst1);
    }
    __syncthreads();
    bf16x8 af[4], bfr[4];
#pragma unroll
    for (int mi = 0; mi < 4; ++mi)
      af[mi] = *(const bf16x8*)(Abuf + (wr * 4 + mi) * 512 + lane * 8);
#pragma unroll
    for (int nj = 0; nj < 4; ++nj)
      bfr[nj] = *(const bf16x8*)(Bbuf + (wc * 4 + nj) * 512 + lane * 8);
#pragma unroll
    for (int mi = 0; mi < 4; ++mi)
#pragma unroll
      for (int nj = 0; nj < 4; ++nj)
        acc[mi][nj] = __builtin_amdgcn_mfma_f32_16x16x32_bf16(
            af[mi], bfr[nj], acc[mi][nj], 0, 0, 0);
    __syncthreads();
  }

#pragma unroll
  for (int nj = 0; nj < 4; ++nj) {
    const int n = col0 + wc * 64 + nj * 16 + (lane & 15);
    const float bb = BIAS ? ((n < nbias) ? bias[n] : 0.f) : 0.f;
#pragma unroll
    for (int mi = 0; mi < 4; ++mi) {
      f32x4 v = acc[mi][nj];
#pragma unroll
      for (int r = 0; r < 4; ++r) {
        const int m = row0 + wr * 64 + mi * 16 + (lane >> 4) * 4 + r;
        float val = v[r] + bb;
        if (RELU) val = fmaxf(val, 0.f);
        if (ZC0 && n == 0) val = 0.f;
        if (OUTF32) C[(size_t)m * N + n] = val;
        if (OUTBF16) Cb[(size_t)m * N + n] = f2bf(val);
      }
    }
  }
}

// ---------------- pre-cast kernels ----------------
__global__ __launch_bounds__(256) void gather_all_k(
    const int* __restrict__ qid, const int* __restrict__ kid,
    const float* __restrict__ emb, ushort_t* __restrict__ gq,
    ushort_t* __restrict__ gk) {
  int m = blockIdx.x;
  const int* ids;
  ushort_t* outp;
  if (m < MQT) {
    ids = qid + m * 3;
    outp = gq + (size_t)m * KP;
  } else {
    m -= MQT;
    ids = kid + m * 3;
    outp = gk + (size_t)m * KP;
  }
  const int t = threadIdx.x;
  if (t >= KP / 4) return;
  const int k = t * 4;
  ushort4 o = make_ushort4(0, 0, 0, 0);
  if (k < KIN) {
    const int node = (k >= 600) ? 2 : ((k >= 300) ? 1 : 0);
    const int off = k - node * 300;
    const int id = ids[node];
    float4 v = *(const float4*)(emb + (size_t)id * 300 + off);
    if (v.x != v.x) v.x = 0.f;
    if (v.y != v.y) v.y = 0.f;
    if (v.z != v.z) v.z = 0.f;
    if (v.w != v.w) v.w = 0.f;
    o = make_ushort4(f2bf(v.x), f2bf(v.y), f2bf(v.z), f2bf(v.w));
  }
  *(ushort4*)(outp + k) = o;
}

// merged transpose-cast, 10 jobs
__global__ __launch_bounds__(256) void tcast10_k(
    const float* __restrict__ q2h_w, const float* __restrict__ k2h_w,
    const float* __restrict__ Wk, const float* __restrict__ Wq,
    const float* __restrict__ p1w, const float* __restrict__ p2w,
    ushort_t* __restrict__ q2h_wt, ushort_t* __restrict__ k2h_wt,
    ushort_t* __restrict__ Wkt, ushort_t* __restrict__ Wqt,
    ushort_t* __restrict__ p1wt, ushort_t* __restrict__ p2wt) {
  const int z = blockIdx.z;
  const float* src;
  ushort_t* dst;
  int R, Cc, Rp, Cp;
  if (z == 0)      { src = q2h_w; dst = q2h_wt; R = KIN;  Cc = HID;  Rp = KP;   Cp = HID; }
  else if (z == 1) { src = k2h_w; dst = k2h_wt; R = KIN;  Cc = HID;  Rp = KP;   Cp = HID; }
  else if (z < 5)  { int i = z - 2; src = Wk + (size_t)i * HID * HID; dst = Wkt + (size_t)i * HID * HID; R = HID; Cc = HID; Rp = HID; Cp = HID; }
  else if (z < 8)  { int i = z - 5; src = Wq + (size_t)i * HID * HID; dst = Wqt + (size_t)i * HID * HID; R = HID; Cc = HID; Rp = HID; Cp = HID; }
  else if (z == 8) { src = p1w; dst = p1wt; R = 1024; Cc = HID;  Rp = 1024; Cp = HID; }
  else             { src = p2w; dst = p2wt; R = HID;  Cc = NOUT; Rp = HID;  Cp = NOUTP; }
  const int r0 = blockIdx.y * 32, c0 = blockIdx.x * 32;
  if (r0 >= Rp || c0 >= Cp) return;
  __shared__ float t[32][33];
  const int tx = threadIdx.x & 31, ty = threadIdx.x >> 5;
#pragma unroll
  for (int i = 0; i < 4; ++i) {
    int r = r0 + ty + i * 8, c = c0 + tx;
    t[ty + i * 8][tx] = (r < R && c < Cc) ? src[(size_t)r * Cc + c] : 0.f;
  }
  __syncthreads();
#pragma unroll
  for (int i = 0; i < 4; ++i) {
    int c = c0 + ty + i * 8, r = r0 + tx;
    if (c < Cp && r < Rp) dst[(size_t)c * Rp + r] = f2bf(t[tx][ty + i * 8]);
  }
}

// ---------------- fused attention, bf16 state, 512 threads ----------------
__global__ __launch_bounds__(512) void att_fused_k(
    const ushort_t* __restrict__ Kta, const ushort_t* __restrict__ Qba,
    const ushort_t* __restrict__ Qbc, const ushort_t* __restrict__ Ktc,
    ushort_t* __restrict__ KtaW, ushort_t* __restrict__ QbaW) {
  const int b = blockIdx.x;
  __shared__ float S_lds[NK][33];        // scores -> Pk in place (13.2 KB)
  __shared__ float Pq[NQ][NK + 4];       // 12.5 KB
  __shared__ __align__(16) ushort_t qts[NQ * HID];  // 30 KB
  const int tid = threadIdx.x;
  const int w = tid >> 6, lane = tid & 63;

  // ---- phase 1: S = SCALE*kp@qp^T (MFMA, waves 0-6); wave7 stages qt_old ----
  {
    const int r = lane & 15, kq = lane >> 4;
    const ushort_t* kpb = Kta + (size_t)b * NK * HID;
    const ushort_t* qpb = Qba + (size_t)b * NQ * HID;
    if (w == 7) {
      const uint4* src = (const uint4*)(Qbc + (size_t)b * NQ * HID);
      uint4* dst = (uint4*)qts;
#pragma unroll
      for (int it = 0; it < 30; ++it) dst[it * 64 + lane] = src[it * 64 + lane];
    } else {
      const int rowA = w * 16 + r;
      const int rowA_c = (rowA < NK) ? rowA : (NK - 1);
      const int qr1 = (16 + r) < NQ ? (16 + r) : NQ - 1;
      f32x4 a0 = {0.f, 0.f, 0.f, 0.f}, a1 = {0.f, 0.f, 0.f, 0.f};
      for (int k0 = 0; k0 < HID; k0 += 32) {
        bf16x8 af = *(const bf16x8*)(kpb + (size_t)rowA_c * HID + k0 + kq * 8);
        bf16x8 b0 = *(const bf16x8*)(qpb + (size_t)r * HID + k0 + kq * 8);
        bf16x8 b1 = *(const bf16x8*)(qpb + (size_t)qr1 * HID + k0 + kq * 8);
        a0 = __builtin_amdgcn_mfma_f32_16x16x32_bf16(af, b0, a0, 0, 0, 0);
        a1 = __builtin_amdgcn_mfma_f32_16x16x32_bf16(af, b1, a1, 0, 0, 0);
      }
      const int q0 = lane & 15, mb = (lane >> 4) * 4;
#pragma unroll
      for (int rr = 0; rr < 4; ++rr) {
        const int mA = w * 16 + mb + rr;
        if (mA < NK) {
          S_lds[mA][q0] = a0[rr] * SCALE;
          if (q0 + 16 < NQ) S_lds[mA][q0 + 16] = a1[rr] * SCALE;
        }
      }
    }
  }
  __syncthreads();
  // ---- phase 2a: Pq (softmax over kr per q) ----
  if (tid < NQ) {
    const int q = tid;
    float m = -1e30f;
    for (int kr = 0; kr < NK; ++kr) m = fmaxf(m, S_lds[kr][q]);
    float s = 0.f;
    for (int kr = 0; kr < NK; ++kr) {
      float e = expf(S_lds[kr][q] - m);
      Pq[q][kr] = e;
      s += e;
    }
    float inv = 1.f / s;
    for (int kr = 0; kr < NK; ++kr) Pq[q][kr] *= inv;
  }
  __syncthreads();
  // ---- phase 2b: Pk in place ----
  if (tid < NK) {
    const int kr = tid;
    float m = -1e30f;
#pragma unroll
    for (int q = 0; q < NQ; ++q) m = fmaxf(m, S_lds[kr][q]);
    float s = 0.f;
    float e[NQ];
#pragma unroll
    for (int q = 0; q < NQ; ++q) {
      e[q] = expf(S_lds[kr][q] - m);
      s += e[q];
    }
    float inv = 1.f / s;
#pragma unroll
    for (int q = 0; q < NQ; ++q) S_lds[kr][q] = e[q] * inv;
  }
  __syncthreads();

  const ushort_t* ktc = Ktc + (size_t)b * NK * HID;
  if (tid < 256) {
    // ---- phase 3 (waves 0-3): att_q = Pq @ kt_old + qt_old ----
    const int c2 = tid;
    float ax[NQ], ay[NQ];
#pragma unroll
    for (int q = 0; q < NQ; ++q) { ax[q] = 0.f; ay[q] = 0.f; }
    for (int kr = 0; kr < NK; ++kr) {
      unsigned int u = *(const unsigned int*)(ktc + (size_t)kr * HID + c2 * 2);
      float kx = bf2f((unsigned short)(u & 0xFFFFu));
      float ky = bf2f((unsigned short)(u >> 16));
#pragma unroll
      for (int q = 0; q < NQ; ++q) {
        float p = Pq[q][kr];
        ax[q] = fmaf(p, kx, ax[q]);
        ay[q] = fmaf(p, ky, ay[q]);
      }
    }
    ushort_t* qout = QbaW + (size_t)b * NQ * HID;
#pragma unroll
    for (int q = 0; q < NQ; ++q) {
      unsigned int u = *(const unsigned int*)(qts + q * HID + c2 * 2);
      float rx = bf2f((unsigned short)(u & 0xFFFFu));
      float ry = bf2f((unsigned short)(u >> 16));
      *(ushort2*)(qout + (size_t)q * HID + c2 * 2) =
          make_ushort2(f2bf(ax[q] + rx), f2bf(ay[q] + ry));
    }
  } else {
    // ---- phase 4 (waves 4-7): att_k = Pk @ qt_old + kt_old ----
    const int c2 = tid - 256;
    float qx[NQ], qy[NQ];
#pragma unroll
    for (int q = 0; q < NQ; ++q) {
      unsigned int u = *(const unsigned int*)(qts + q * HID + c2 * 2);
      qx[q] = bf2f((unsigned short)(u & 0xFFFFu));
      qy[q] = bf2f((unsigned short)(u >> 16));
    }
    ushort_t* kout = KtaW + (size_t)b * NK * HID;
    for (int kr = 0; kr < NK; ++kr) {
      unsigned int u = *(const unsigned int*)(ktc + (size_t)kr * HID + c2 * 2);
      float sx = bf2f((unsigned short)(u & 0xFFFFu));
      float sy = bf2f((unsigned short)(u >> 16));
#pragma unroll
      for (int q = 0; q < NQ; ++q) {
        float p = S_lds[kr][q];
        sx = fmaf(p, qx[q], sx);
        sy = fmaf(p, qy[q], sy);
      }
      *(ushort2*)(kout + (size_t)kr * HID + c2 * 2) =
          make_ushort2(f2bf(sx), f2bf(sy));
    }
  }
}

// ---------------- fused boundary v2: parallel row-norms ----------------
// 512 threads. Pass 1: 130 row sum-squares via per-wave reduce (col0 of
// state is exactly 0, so whole-row sumsq is correct). Pass 2: column-owner
// accumulation of the expmapped means; thread 0 handles the time component.
// Then one block-reduce for the logmap norm.
__global__ __launch_bounds__(512) void finale_k(
    const ushort_t* __restrict__ Kb, const ushort_t* __restrict__ Qb,
    ushort_t* __restrict__ lastb, const float* __restrict__ curv) {
  const int b = blockIdx.x, tid = threadIdx.x;
  const int w = tid >> 6, lane = tid & 63;
  const float c = curv[NLAYERS];
  const float Kc = 1.f / c, sqrtK = sqrtf(Kc);
  __shared__ float fsc[NK + NQ];   // spatial scale per row
  __shared__ float fst[NK + NQ];   // time component per row
  const ushort_t* xkp = Kb + (size_t)b * NK * HID;
  const ushort_t* xqp = Qb + (size_t)b * NQ * HID;

  // pass 1: rows striped over 8 waves; wave-reduce only
  for (int r = w; r < NK + NQ; r += 8) {
    const ushort_t* row =
        (r < NK) ? (xkp + (size_t)r * HID) : (xqp + (size_t)(r - NK) * HID);
    bf16x8 v = *(const bf16x8*)(row + lane * 8);
    float ss = 0.f;
#pragma unroll
    for (int j = 0; j < 8; ++j) {
      float t = bf2f((unsigned short)v[j]);
      ss = fmaf(t, t, ss);
    }
    ss = waveReduceSum(ss);
    if (lane == 0) {
      float n = fmaxf(sqrtf(ss), 1e-15f);
      float f = sqrtK * sinhf(n / sqrtK) / n;
      fsc[r] = f;
      fst[r] = sqrtf(fmaxf(Kc + f * f * ss, 1e-7f));
    }
  }
  __syncthreads();

  // pass 2: thread owns column `tid` (512 cols); accumulate means
  float mk, mq;
  if (tid == 0) {
    float sk = 0.f, sq2 = 0.f;
    for (int r = 0; r < NK; ++r) sk += fst[r];
    for (int r = 0; r < NQ; ++r) sq2 += fst[NK + r];
    mk = sk;
    mq = sq2;
  } else {
    float sk = 0.f, sq2 = 0.f;
    for (int r = 0; r < NK; ++r)
      sk = fmaf(fsc[r], bf2f(xkp[(size_t)r * HID + tid]), sk);
    for (int r = 0; r < NQ; ++r)
      sq2 = fmaf(fsc[NK + r], bf2f(xqp[(size_t)r * HID + tid]), sq2);
    mk = sk;
    mq = sq2;
  }
  mk *= (1.f / NK);
  mq *= (1.f / NQ);

  // logmap0 on the 1024 concat [mk(512) | mq(512)]; element 0 = time comp
  float sq = ((tid == 0) ? 0.f : mk * mk) + mq * mq;
  float ssall = blockReduceSum512(sq);
  __shared__ float x0sh;
  if (tid == 0) x0sh = mk;
  __syncthreads();
  const float x0 = x0sh;
  const float n = fmaxf(sqrtf(ssall), 1e-15f);
  const float theta = fmaxf(x0 / sqrtK, 1.f + 1e-7f);
  const float rr = sqrtK * acoshf(theta) / n;
  ushort_t* ob = lastb + (size_t)b * 1024;
  ob[tid] = (tid == 0) ? (ushort_t)0 : f2bf(rr * mk);
  ob[512 + tid] = f2bf(rr * mq);
}

// ---------------- tail: 2-pass online log-softmax ----------------
__global__ __launch_bounds__(512) void logsoftmax_k(float* __restrict__ x) {
  const int b = blockIdx.x, tid = threadIdx.x;
  float4* row = (float4*)(x + (size_t)b * NANS);
  // pass 1: online max+sum
  float m = -3.4e38f, s = 0.f;
  for (int i = tid; i < NANS / 4; i += 512) {
    float4 v = row[i];
    float lm = fmaxf(fmaxf(v.x, v.y), fmaxf(v.z, v.w));
    float nm = fmaxf(m, lm);
    s = s * expf(m - nm) + expf(v.x - nm) + expf(v.y - nm) +
        expf(v.z - nm) + expf(v.w - nm);
    m = nm;
  }
  // combine (m, s) across lanes
#pragma unroll
  for (int o = 32; o > 0; o >>= 1) {
    float mo = __shfl_xor(m, o);
    float so = __shfl_xor(s, o);
    float nm = fmaxf(m, mo);
    s = s * expf(m - nm) + so * expf(mo - nm);
    m = nm;
  }
  __shared__ float smm[8], sms[8];
  const int w = tid >> 6, lane = tid & 63;
  if (lane == 0) { smm[w] = m; sms[w] = s; }
  __syncthreads();
  float gm = smm[0], gs = sms[0];
#pragma unroll
  for (int i = 1; i < 8; ++i) {
    float nm = fmaxf(gm, smm[i]);
    gs = gs * expf(gm - nm) + sms[i] * expf(smm[i] - nm);
    gm = nm;
  }
  const float lse = gm + logf(gs);
  // pass 2: write
  for (int i = tid; i < NANS / 4; i += 512) {
    float4 v = row[i];
    v.x -= lse; v.y -= lse; v.z -= lse; v.w -= lse;
    row[i] = v;
  }
}

// ---------------- launch ----------------
extern "C" void kernel_launch(void* const* d_in, const int* in_sizes, int n_in,
                              void* d_out, int out_size, void* d_ws, size_t ws_size,
                              hipStream_t stream) {
  const int* qid = (const int*)d_in[0];
  const int* kid = (const int*)d_in[1];
  const float* emb = (const float*)d_in[2];
  const float* q2h_w = (const float*)d_in[3];
  const float* q2h_b = (const float*)d_in[4];
  const float* k2h_w = (const float*)d_in[5];
  const float* k2h_b = (const float*)d_in[6];
  const float* Wk = (const float*)d_in[7];
  const float* Wq = (const float*)d_in[8];
  const float* curv = (const float*)d_in[9];
  const float* p1w = (const float*)d_in[10];
  const float* p1b = (const float*)d_in[11];
  const float* p2w = (const float*)d_in[12];
  const float* p2b = (const float*)d_in[13];
  const float* glove = (const float*)d_in[14];
  float* out = (float*)d_out;

  // ---- workspace layout (all bf16) ----
  ushort_t* u = (ushort_t*)d_ws;
  ushort_t* Kb0 = u;                           // 25600*512 (k-state ping)
  ushort_t* Kb1 = Kb0 + (size_t)MKT * HID;     // 25600*512 (k-state pong / kp)
  ushort_t* qb0 = Kb1 + (size_t)MKT * HID;     // 7680*512 (q-state ping)
  ushort_t* qb1 = qb0 + (size_t)MQT * HID;     // 7680*512 (q-state pong / qp)
  ushort_t* gq = qb1 + (size_t)MQT * HID;      // 7680*928
  ushort_t* gk = gq + (size_t)MQT * KP;        // 25600*928
  ushort_t* q2h_wt = gk + (size_t)MKT * KP;    // 928*512 (stored [N][K])
  ushort_t* k2h_wt = q2h_wt + (size_t)HID * KP;
  ushort_t* Wkt = k2h_wt + (size_t)HID * KP;   // 3*512*512
  ushort_t* Wqt = Wkt + (size_t)NLAYERS * HID * HID;
  ushort_t* p1wt = Wqt + (size_t)NLAYERS * HID * HID;   // 512*1024
  ushort_t* p2wt = p1wt + (size_t)HID * 1024;           // 384*512
  ushort_t* lastb = p2wt + (size_t)NOUTP * HID;         // 256*1024
  ushort_t* h1b = lastb + (size_t)BATCH * 1024;         // 256*512
  ushort_t* o2b = h1b + (size_t)BATCH * HID;            // 256*384

  // ---- pre-casts ----
  gather_all_k<<<MQT + MKT, 256, 0, stream>>>(qid, kid, emb, gq, gk);
  tcast10_k<<<dim3(16, 32, 10), 256, 0, stream>>>(
      q2h_w, k2h_w, Wk, Wq, p1w, p2w, q2h_wt, k2h_wt, Wkt, Wqt, p1wt, p2wt);

  // ---- input projections (merged q+k), fused proj_tan0, bf16 out only ----
  mfma_gemm2<0, 1, 0, 1, 1, 0><<<dim3(HID / 128, MQT / 128 + MKT / 128), 256, 0, stream>>>(
      gq, q2h_wt, q2h_b, nullptr, qb0, MQT / 128,
      gk, k2h_wt, k2h_b, nullptr, Kb0, nullptr, HID, KP, HID);

  // ---- layers in tangent space (bf16 state ping-pong) ----
  ushort_t* Kc = Kb0;
  ushort_t* Ka = Kb1;
  ushort_t* Qc = qb0;
  ushort_t* Qa = qb1;
  for (int i = 0; i < NLAYERS; ++i) {
    mfma_gemm2<0, 0, 0, 1, 0, 0><<<dim3(HID / 128, MKT / 128 + MQT / 128), 256, 0, stream>>>(
        Kc, Wkt + (size_t)i * HID * HID, nullptr, nullptr, Ka, MKT / 128,
        Qc, Wqt + (size_t)i * HID * HID, nullptr, nullptr, Qa,
        nullptr, HID, HID, HID);
    att_fused_k<<<BATCH, 512, 0, stream>>>(Ka, Qa, Qc, Kc, Ka, Qa);
    ushort_t* t1 = Kc; Kc = Ka; Ka = t1;
    ushort_t* t2 = Qc; Qc = Qa; Qa = t2;
  }

  // ---- fused boundary (expproj + mean + logmap) -> lastb bf16 ----
  finale_k<<<BATCH, 512, 0, stream>>>(Kc, Qc, lastb, curv);

  // ---- head (all MFMA bf16) ----
  mfma_gemm2<0, 1, 0, 1, 0, 1><<<dim3(HID / 128, BATCH / 128), 256, 0, stream>>>(
      lastb, p1wt, p1b, nullptr, h1b, BATCH / 128,
      lastb, p1wt, p1b, nullptr, h1b, nullptr, HID, 1024, HID);
  mfma_gemm2<0, 1, 0, 1, 0, 0><<<dim3(NOUTP / 128, BATCH / 128), 256, 0, stream>>>(
      h1b, p2wt, p2b, nullptr, o2b, BATCH / 128,
      h1b, p2wt, p2b, nullptr, o2b, nullptr, NOUTP, HID, NOUT);
  // sim: B staged directly from f32 glove (cast in-register)
  mfma_gemm2<1, 0, 1, 0, 0, 0><<<dim3(NANS / 128, BATCH / 128), 256, 0, stream>>>(
      o2b, nullptr, nullptr, out, nullptr, BATCH / 128,
      o2b, nullptr, nullptr, out, nullptr, glove, NANS, NOUTP, NANS);
  logsoftmax_k<<<BATCH, 512, 0, stream>>>(out);
}

// Round 10
// 586.136 us; speedup vs baseline: 1.2853x; 1.0031x over previous
//
#include <hip/hip_runtime.h>
#include <math.h>

// Problem constants (from setup_inputs)
#define BATCH 256
#define NQ 30
#define NK 100
#define HID 512
#define WORD 300
#define KIN 900          // WORD*3
#define KP 928           // KIN padded to multiple of 32
#define NANS 32000
#define NOUT 300
#define NOUTP 384        // NOUT padded to multiple of 128 (MFMA N-tile)
#define NLAYERS 3
#define MQT (BATCH * NQ)   // 7680
#define MKT (BATCH * NK)   // 25600
#define SCALE 0.044194173824159216f  // 1/sqrt(512)
#define CHW 256            // columns per attention chunk-block

typedef __attribute__((ext_vector_type(8))) short bf16x8;
typedef __attribute__((ext_vector_type(4))) float f32x4;
typedef unsigned short ushort_t;

__device__ __forceinline__ unsigned short f2bf(float f) {
  unsigned int u = __float_as_uint(f);
  u = (u + 0x7FFF + ((u >> 16) & 1)) >> 16;  // RNE
  return (unsigned short)u;
}
__device__ __forceinline__ float bf2f(unsigned short s) {
  return __uint_as_float(((unsigned int)s) << 16);
}

typedef const __attribute__((address_space(1))) unsigned int* gas_u32;
typedef __attribute__((address_space(3))) unsigned int* las_u32;
__device__ __forceinline__ void gld_lds16(const void* g, void* l) {
  __builtin_amdgcn_global_load_lds((gas_u32)g, (las_u32)l, 16, 0, 0);
}

// bijective XCD swizzle (m204)
__device__ __forceinline__ int xcd_swz_linear() {
  const int nwg = gridDim.x * gridDim.y;
  const int orig = blockIdx.y * gridDim.x + blockIdx.x;
  const int q = nwg >> 3, r = nwg & 7;
  const int xcd = orig & 7, idx = orig >> 3;
  return (xcd < r ? xcd * (q + 1) : r * (q + 1) + (xcd - r) * q) + idx;
}

// ---------------- reduction helpers ----------------
__device__ __forceinline__ float waveReduceSum(float v) {
#pragma unroll
  for (int o = 32; o > 0; o >>= 1) v += __shfl_xor(v, o);
  return v;
}
__device__ float blockReduceSum512(float v) {
  __shared__ float sm[8];
  int lane = threadIdx.x & 63, w = threadIdx.x >> 6;
  v = waveReduceSum(v);
  if (lane == 0) sm[w] = v;
  __syncthreads();
  float r = 0.f;
#pragma unroll
  for (int i = 0; i < 8; ++i) r += sm[i];
  __syncthreads();
  return r;
}

// cast 8 f32 from a glove row (length NOUT, zero-pad beyond) to bf16x8
__device__ __forceinline__ bf16x8 castrow8(const float* __restrict__ rowp, int kb) {
  union { ushort_t u[8]; bf16x8 v; } pk;
  if (kb + 8 <= NOUT) {
    float2 a0 = *(const float2*)(rowp + kb);
    float2 a1 = *(const float2*)(rowp + kb + 2);
    float2 a2 = *(const float2*)(rowp + kb + 4);
    float2 a3 = *(const float2*)(rowp + kb + 6);
    pk.u[0] = f2bf(a0.x); pk.u[1] = f2bf(a0.y);
    pk.u[2] = f2bf(a1.x); pk.u[3] = f2bf(a1.y);
    pk.u[4] = f2bf(a2.x); pk.u[5] = f2bf(a2.y);
    pk.u[6] = f2bf(a3.x); pk.u[7] = f2bf(a3.y);
  } else {
#pragma unroll
    for (int j = 0; j < 8; ++j) {
      const int kk = kb + j;
      pk.u[j] = (kk < NOUT) ? f2bf(rowp[kk]) : (ushort_t)0;
    }
  }
  return pk.v;
}

// ---------------- bf16 MFMA GEMM (dual operand-set, XCD-swizzled) ----------
template <int BF32B, int BIAS, int OUTF32, int OUTBF16, int ZC0, int RELU>
__global__ __launch_bounds__(256) void mfma_gemm2(
    const ushort_t* __restrict__ A1, const ushort_t* __restrict__ Bt1,
    const float* __restrict__ bias1, float* __restrict__ C1,
    ushort_t* __restrict__ Cb1, int M1b,
    const ushort_t* __restrict__ A2, const ushort_t* __restrict__ Bt2,
    const float* __restrict__ bias2, float* __restrict__ C2,
    ushort_t* __restrict__ Cb2, const float* __restrict__ Bf,
    int N, int K, int nbias) {
  __shared__ __align__(16) ushort_t Abuf[128 * 32];
  __shared__ __align__(16) ushort_t Bbuf[128 * 32];
  const int wg = xcd_swz_linear();
  const int bx = wg % gridDim.x, by = wg / gridDim.x;
  const bool sel = (by >= M1b);
  const ushort_t* A = sel ? A2 : A1;
  const ushort_t* Bt = sel ? Bt2 : Bt1;
  const float* bias = sel ? bias2 : bias1;
  float* C = sel ? C2 : C1;
  ushort_t* Cb = sel ? Cb2 : Cb1;
  const int row0 = (sel ? (by - M1b) : by) * 128;
  const int col0 = bx * 128;

  const int tid = threadIdx.x;
  const int lane = tid & 63, w = tid >> 6;
  const int wr = w >> 1, wc = w & 1;
  const int s_r = lane & 15, s_kq = lane >> 4;

  const size_t a_src0 = (size_t)(row0 + (w * 2 + 0) * 16 + s_r) * K + s_kq * 8;
  const size_t a_src1 = (size_t)(row0 + (w * 2 + 1) * 16 + s_r) * K + s_kq * 8;
  const size_t b_src0 = (size_t)(col0 + (w * 2 + 0) * 16 + s_r) * K + s_kq * 8;
  const size_t b_src1 = (size_t)(col0 + (w * 2 + 1) * 16 + s_r) * K + s_kq * 8;
  ushort_t* a_dst0 = Abuf + (w * 2 + 0) * 512;
  ushort_t* a_dst1 = Abuf + (w * 2 + 1) * 512;
  ushort_t* b_dst0 = Bbuf + (w * 2 + 0) * 512;
  ushort_t* b_dst1 = Bbuf + (w * 2 + 1) * 512;
  const float* bf_row0 = BF32B ? (Bf + (size_t)(col0 + (w * 2 + 0) * 16 + s_r) * NOUT) : nullptr;
  const float* bf_row1 = BF32B ? (Bf + (size_t)(col0 + (w * 2 + 1) * 16 + s_r) * NOUT) : nullptr;

  f32x4 acc[4][4];
#pragma unroll
  for (int i = 0; i < 4; ++i)
#pragma unroll
    for (int j = 0; j < 4; ++j) acc[i][j] = (f32x4){0.f, 0.f, 0.f, 0.f};

  for (int k0 = 0; k0 < K; k0 += 32) {
    gld_lds16(A + a_src0 + k0, a_dst0);
    gld_lds16(A + a_src1 + k0, a_dst1);
    if (BF32B) {
      const int kb = k0 + s_kq * 8;
      *(bf16x8*)(b_dst0 + lane * 8) = castrow8(bf_row0, kb);
      *(bf16x8*)(b_dst1 + lane * 8) = castrow8(bf_row1, kb);
    } else {
      gld_lds16(Bt + b_src0 + k0, b_dst0);
      gld_lds16(Bt + b_src1 + k0, b_dst1);
    }
    __syncthreads();
    bf16x8 af[4], bfr[4];
#pragma unroll
    for (int mi = 0; mi < 4; ++mi)
      af[mi] = *(const bf16x8*)(Abuf + (wr * 4 + mi) * 512 + lane * 8);
#pragma unroll
    for (int nj = 0; nj < 4; ++nj)
      bfr[nj] = *(const bf16x8*)(Bbuf + (wc * 4 + nj) * 512 + lane * 8);
#pragma unroll
    for (int mi = 0; mi < 4; ++mi)
#pragma unroll
      for (int nj = 0; nj < 4; ++nj)
        acc[mi][nj] = __builtin_amdgcn_mfma_f32_16x16x32_bf16(
            af[mi], bfr[nj], acc[mi][nj], 0, 0, 0);
    __syncthreads();
  }

#pragma unroll
  for (int nj = 0; nj < 4; ++nj) {
    const int n = col0 + wc * 64 + nj * 16 + (lane & 15);
    const float bb = BIAS ? ((n < nbias) ? bias[n] : 0.f) : 0.f;
#pragma unroll
    for (int mi = 0; mi < 4; ++mi) {
      f32x4 v = acc[mi][nj];
#pragma unroll
      for (int r = 0; r < 4; ++r) {
        const int m = row0 + wr * 64 + mi * 16 + (lane >> 4) * 4 + r;
        float val = v[r] + bb;
        if (RELU) val = fmaxf(val, 0.f);
        if (ZC0 && n == 0) val = 0.f;
        if (OUTF32) C[(size_t)m * N + n] = val;
        if (OUTBF16) Cb[(size_t)m * N + n] = f2bf(val);
      }
    }
  }
}

// ---------------- pre-cast kernels ----------------
__global__ __launch_bounds__(256) void gather_all_k(
    const int* __restrict__ qid, const int* __restrict__ kid,
    const float* __restrict__ emb, ushort_t* __restrict__ gq,
    ushort_t* __restrict__ gk) {
  int m = blockIdx.x;
  const int* ids;
  ushort_t* outp;
  if (m < MQT) {
    ids = qid + m * 3;
    outp = gq + (size_t)m * KP;
  } else {
    m -= MQT;
    ids = kid + m * 3;
    outp = gk + (size_t)m * KP;
  }
  const int t = threadIdx.x;
  if (t >= KP / 4) return;
  const int k = t * 4;
  ushort4 o = make_ushort4(0, 0, 0, 0);
  if (k < KIN) {
    const int node = (k >= 600) ? 2 : ((k >= 300) ? 1 : 0);
    const int off = k - node * 300;
    const int id = ids[node];
    float4 v = *(const float4*)(emb + (size_t)id * 300 + off);
    if (v.x != v.x) v.x = 0.f;
    if (v.y != v.y) v.y = 0.f;
    if (v.z != v.z) v.z = 0.f;
    if (v.w != v.w) v.w = 0.f;
    o = make_ushort4(f2bf(v.x), f2bf(v.y), f2bf(v.z), f2bf(v.w));
  }
  *(ushort4*)(outp + k) = o;
}

// merged transpose-cast, 10 jobs
__global__ __launch_bounds__(256) void tcast10_k(
    const float* __restrict__ q2h_w, const float* __restrict__ k2h_w,
    const float* __restrict__ Wk, const float* __restrict__ Wq,
    const float* __restrict__ p1w, const float* __restrict__ p2w,
    ushort_t* __restrict__ q2h_wt, ushort_t* __restrict__ k2h_wt,
    ushort_t* __restrict__ Wkt, ushort_t* __restrict__ Wqt,
    ushort_t* __restrict__ p1wt, ushort_t* __restrict__ p2wt) {
  const int z = blockIdx.z;
  const float* src;
  ushort_t* dst;
  int R, Cc, Rp, Cp;
  if (z == 0)      { src = q2h_w; dst = q2h_wt; R = KIN;  Cc = HID;  Rp = KP;   Cp = HID; }
  else if (z == 1) { src = k2h_w; dst = k2h_wt; R = KIN;  Cc = HID;  Rp = KP;   Cp = HID; }
  else if (z < 5)  { int i = z - 2; src = Wk + (size_t)i * HID * HID; dst = Wkt + (size_t)i * HID * HID; R = HID; Cc = HID; Rp = HID; Cp = HID; }
  else if (z < 8)  { int i = z - 5; src = Wq + (size_t)i * HID * HID; dst = Wqt + (size_t)i * HID * HID; R = HID; Cc = HID; Rp = HID; Cp = HID; }
  else if (z == 8) { src = p1w; dst = p1wt; R = 1024; Cc = HID;  Rp = 1024; Cp = HID; }
  else             { src = p2w; dst = p2wt; R = HID;  Cc = NOUT; Rp = HID;  Cp = NOUTP; }
  const int r0 = blockIdx.y * 32, c0 = blockIdx.x * 32;
  if (r0 >= Rp || c0 >= Cp) return;
  __shared__ float t[32][33];
  const int tx = threadIdx.x & 31, ty = threadIdx.x >> 5;
#pragma unroll
  for (int i = 0; i < 4; ++i) {
    int r = r0 + ty + i * 8, c = c0 + tx;
    t[ty + i * 8][tx] = (r < R && c < Cc) ? src[(size_t)r * Cc + c] : 0.f;
  }
  __syncthreads();
#pragma unroll
  for (int i = 0; i < 4; ++i) {
    int c = c0 + ty + i * 8, r = r0 + tx;
    if (c < Cp && r < Rp) dst[(size_t)c * Rp + r] = f2bf(t[tx][ty + i * 8]);
  }
}

// ---------------- fused attention v3: 2 chunk-blocks per batch ------------
// grid (2, BATCH), 512 threads. Kp=kp, Qp=qp (proj scratch), Qc/Ktc = old
// state, Kn/Qn = new state (separate buffers -> no cross-block race).
// phase1: S = SCALE*kp@qp^T (MFMA, waves 0-6) -> S_lds [NK][32]
// phase2a: Pq transposed -> PqT[kr][q] (cols 30,31 zeroed)
// phase2b: Pk softmax rows in place in S_lds (cols 30,31 zeroed)
// phase3 (thr 0-255): att_q col c = c0+tid; phase4 (thr 256-511): att_k
__global__ __launch_bounds__(512) void att_fused_k(
    const ushort_t* __restrict__ Kp, const ushort_t* __restrict__ Qp,
    const ushort_t* __restrict__ Qc, const ushort_t* __restrict__ Ktc,
    ushort_t* __restrict__ Kn, ushort_t* __restrict__ Qn) {
  const int b = blockIdx.y;
  const int c0 = blockIdx.x * CHW;
  __shared__ float S_lds[NK][32];   // 12.8 KB
  __shared__ float PqT[NK][32];     // 12.8 KB
  const int tid = threadIdx.x;
  const int w = tid >> 6, lane = tid & 63;

  // ---- phase 1: S (waves 0-6) ----
  if (w < 7) {
    const int r = lane & 15, kq = lane >> 4;
    const ushort_t* kpb = Kp + (size_t)b * NK * HID;
    const ushort_t* qpb = Qp + (size_t)b * NQ * HID;
    const int rowA = w * 16 + r;
    const int rowA_c = (rowA < NK) ? rowA : (NK - 1);
    const int qr1 = (16 + r) < NQ ? (16 + r) : NQ - 1;
    f32x4 a0 = {0.f, 0.f, 0.f, 0.f}, a1 = {0.f, 0.f, 0.f, 0.f};
    for (int k0 = 0; k0 < HID; k0 += 32) {
      bf16x8 af = *(const bf16x8*)(kpb + (size_t)rowA_c * HID + k0 + kq * 8);
      bf16x8 b0 = *(const bf16x8*)(qpb + (size_t)r * HID + k0 + kq * 8);
      bf16x8 b1 = *(const bf16x8*)(qpb + (size_t)qr1 * HID + k0 + kq * 8);
      a0 = __builtin_amdgcn_mfma_f32_16x16x32_bf16(af, b0, a0, 0, 0, 0);
      a1 = __builtin_amdgcn_mfma_f32_16x16x32_bf16(af, b1, a1, 0, 0, 0);
    }
    const int q0 = lane & 15, mb = (lane >> 4) * 4;
#pragma unroll
    for (int rr = 0; rr < 4; ++rr) {
      const int mA = w * 16 + mb + rr;
      if (mA < NK) {
        S_lds[mA][q0] = a0[rr] * SCALE;
        if (q0 + 16 < NQ) S_lds[mA][q0 + 16] = a1[rr] * SCALE;
      }
    }
  }
  __syncthreads();
  // ---- phase 2a: Pq (softmax over kr, per q), stored TRANSPOSED ----
  if (tid < NQ) {
    const int q = tid;
    float m = -1e30f;
    for (int kr = 0; kr < NK; ++kr) m = fmaxf(m, S_lds[kr][q]);
    float s = 0.f;
    for (int kr = 0; kr < NK; ++kr) {
      float e = expf(S_lds[kr][q] - m);
      PqT[kr][q] = e;
      s += e;
    }
    float inv = 1.f / s;
    for (int kr = 0; kr < NK; ++kr) PqT[kr][q] *= inv;
  } else if (tid >= 32 && tid < 32 + NK) {
    const int kr = tid - 32;
    PqT[kr][30] = 0.f;
    PqT[kr][31] = 0.f;
  }
  __syncthreads();
  // ---- phase 2b: Pk rows in place ----
  if (tid < NK) {
    const int kr = tid;
    float m = -1e30f;
#pragma unroll
    for (int q = 0; q < NQ; ++q) m = fmaxf(m, S_lds[kr][q]);
    float s = 0.f;
    float e[NQ];
#pragma unroll
    for (int q = 0; q < NQ; ++q) {
      e[q] = expf(S_lds[kr][q] - m);
      s += e[q];
    }
    float inv = 1.f / s;
#pragma unroll
    for (int q = 0; q < NQ; ++q) S_lds[kr][q] = e[q] * inv;
    S_lds[kr][30] = 0.f;
    S_lds[kr][31] = 0.f;
  }
  __syncthreads();

  const ushort_t* ktc = Ktc + (size_t)b * NK * HID;
  const ushort_t* qtc = Qc + (size_t)b * NQ * HID;
  if (tid < CHW) {
    // ---- phase 3: att_q, one column per thread ----
    const int c = c0 + tid;
    float ax[32];
#pragma unroll
    for (int i = 0; i < 32; ++i) ax[i] = 0.f;
    for (int kr = 0; kr < NK; ++kr) {
      float kx = bf2f(ktc[(size_t)kr * HID + c]);
#pragma unroll
      for (int g = 0; g < 8; ++g) {
        float4 p = *(const float4*)&PqT[kr][g * 4];
        ax[g * 4 + 0] = fmaf(p.x, kx, ax[g * 4 + 0]);
        ax[g * 4 + 1] = fmaf(p.y, kx, ax[g * 4 + 1]);
        ax[g * 4 + 2] = fmaf(p.z, kx, ax[g * 4 + 2]);
        ax[g * 4 + 3] = fmaf(p.w, kx, ax[g * 4 + 3]);
      }
    }
    ushort_t* qout = Qn + (size_t)b * NQ * HID;
#pragma unroll
    for (int q = 0; q < NQ; ++q) {
      float res = bf2f(qtc[(size_t)q * HID + c]);
      qout[(size_t)q * HID + c] = f2bf(ax[q] + res);
    }
  } else {
    // ---- phase 4: att_k, one column per thread ----
    const int c = c0 + (tid - CHW);
    float qx[32];
#pragma unroll
    for (int q = 0; q < NQ; ++q) qx[q] = bf2f(qtc[(size_t)q * HID + c]);
    qx[30] = 0.f;
    qx[31] = 0.f;
    ushort_t* kout = Kn + (size_t)b * NK * HID;
    for (int kr = 0; kr < NK; ++kr) {
      float sx = bf2f(ktc[(size_t)kr * HID + c]);
#pragma unroll
      for (int g = 0; g < 8; ++g) {
        float4 p = *(const float4*)&S_lds[kr][g * 4];
        sx = fmaf(p.x, qx[g * 4 + 0], sx);
        sx = fmaf(p.y, qx[g * 4 + 1], sx);
        sx = fmaf(p.z, qx[g * 4 + 2], sx);
        sx = fmaf(p.w, qx[g * 4 + 3], sx);
      }
      kout[(size_t)kr * HID + c] = f2bf(sx);
    }
  }
}

// ---------------- fused boundary: parallel row-norms ----------------
__global__ __launch_bounds__(512) void finale_k(
    const ushort_t* __restrict__ Kb, const ushort_t* __restrict__ Qb,
    ushort_t* __restrict__ lastb, const float* __restrict__ curv) {
  const int b = blockIdx.x, tid = threadIdx.x;
  const int w = tid >> 6, lane = tid & 63;
  const float c = curv[NLAYERS];
  const float Kc = 1.f / c, sqrtK = sqrtf(Kc);
  __shared__ float fsc[NK + NQ];
  __shared__ float fst[NK + NQ];
  const ushort_t* xkp = Kb + (size_t)b * NK * HID;
  const ushort_t* xqp = Qb + (size_t)b * NQ * HID;

  for (int r = w; r < NK + NQ; r += 8) {
    const ushort_t* row =
        (r < NK) ? (xkp + (size_t)r * HID) : (xqp + (size_t)(r - NK) * HID);
    bf16x8 v = *(const bf16x8*)(row + lane * 8);
    float ss = 0.f;
#pragma unroll
    for (int j = 0; j < 8; ++j) {
      float t = bf2f((unsigned short)v[j]);
      ss = fmaf(t, t, ss);
    }
    ss = waveReduceSum(ss);
    if (lane == 0) {
      float n = fmaxf(sqrtf(ss), 1e-15f);
      float f = sqrtK * sinhf(n / sqrtK) / n;
      fsc[r] = f;
      fst[r] = sqrtf(fmaxf(Kc + f * f * ss, 1e-7f));
    }
  }
  __syncthreads();

  float mk, mq;
  if (tid == 0) {
    float sk = 0.f, sq2 = 0.f;
    for (int r = 0; r < NK; ++r) sk += fst[r];
    for (int r = 0; r < NQ; ++r) sq2 += fst[NK + r];
    mk = sk;
    mq = sq2;
  } else {
    float sk = 0.f, sq2 = 0.f;
    for (int r = 0; r < NK; ++r)
      sk = fmaf(fsc[r], bf2f(xkp[(size_t)r * HID + tid]), sk);
    for (int r = 0; r < NQ; ++r)
      sq2 = fmaf(fsc[NK + r], bf2f(xqp[(size_t)r * HID + tid]), sq2);
    mk = sk;
    mq = sq2;
  }
  mk *= (1.f / NK);
  mq *= (1.f / NQ);

  float sq = ((tid == 0) ? 0.f : mk * mk) + mq * mq;
  float ssall = blockReduceSum512(sq);
  __shared__ float x0sh;
  if (tid == 0) x0sh = mk;
  __syncthreads();
  const float x0 = x0sh;
  const float n = fmaxf(sqrtf(ssall), 1e-15f);
  const float theta = fmaxf(x0 / sqrtK, 1.f + 1e-7f);
  const float rr = sqrtK * acoshf(theta) / n;
  ushort_t* ob = lastb + (size_t)b * 1024;
  ob[tid] = (tid == 0) ? (ushort_t)0 : f2bf(rr * mk);
  ob[512 + tid] = f2bf(rr * mq);
}

// ---------------- tail: 2-pass online log-softmax ----------------
__global__ __launch_bounds__(512) void logsoftmax_k(float* __restrict__ x) {
  const int b = blockIdx.x, tid = threadIdx.x;
  float4* row = (float4*)(x + (size_t)b * NANS);
  float m = -3.4e38f, s = 0.f;
  for (int i = tid; i < NANS / 4; i += 512) {
    float4 v = row[i];
    float lm = fmaxf(fmaxf(v.x, v.y), fmaxf(v.z, v.w));
    float nm = fmaxf(m, lm);
    s = s * expf(m - nm) + expf(v.x - nm) + expf(v.y - nm) +
        expf(v.z - nm) + expf(v.w - nm);
    m = nm;
  }
#pragma unroll
  for (int o = 32; o > 0; o >>= 1) {
    float mo = __shfl_xor(m, o);
    float so = __shfl_xor(s, o);
    float nm = fmaxf(m, mo);
    s = s * expf(m - nm) + so * expf(mo - nm);
    m = nm;
  }
  __shared__ float smm[8], sms[8];
  const int w = tid >> 6, lane = tid & 63;
  if (lane == 0) { smm[w] = m; sms[w] = s; }
  __syncthreads();
  float gm = smm[0], gs = sms[0];
#pragma unroll
  for (int i = 1; i < 8; ++i) {
    float nm = fmaxf(gm, smm[i]);
    gs = gs * expf(gm - nm) + sms[i] * expf(smm[i] - nm);
    gm = nm;
  }
  const float lse = gm + logf(gs);
  for (int i = tid; i < NANS / 4; i += 512) {
    float4 v = row[i];
    v.x -= lse; v.y -= lse; v.z -= lse; v.w -= lse;
    row[i] = v;
  }
}

// ---------------- launch ----------------
extern "C" void kernel_launch(void* const* d_in, const int* in_sizes, int n_in,
                              void* d_out, int out_size, void* d_ws, size_t ws_size,
                              hipStream_t stream) {
  const int* qid = (const int*)d_in[0];
  const int* kid = (const int*)d_in[1];
  const float* emb = (const float*)d_in[2];
  const float* q2h_w = (const float*)d_in[3];
  const float* q2h_b = (const float*)d_in[4];
  const float* k2h_w = (const float*)d_in[5];
  const float* k2h_b = (const float*)d_in[6];
  const float* Wk = (const float*)d_in[7];
  const float* Wq = (const float*)d_in[8];
  const float* curv = (const float*)d_in[9];
  const float* p1w = (const float*)d_in[10];
  const float* p1b = (const float*)d_in[11];
  const float* p2w = (const float*)d_in[12];
  const float* p2b = (const float*)d_in[13];
  const float* glove = (const float*)d_in[14];
  float* out = (float*)d_out;

  // ---- workspace layout (all bf16) ----
  ushort_t* u = (ushort_t*)d_ws;
  ushort_t* Ks0 = u;                           // 25600*512 (k-state ping)
  ushort_t* Ks1 = Ks0 + (size_t)MKT * HID;     // 25600*512 (k-state pong)
  ushort_t* Kps = Ks1 + (size_t)MKT * HID;     // 25600*512 (kp scratch)
  ushort_t* Qs0 = Kps + (size_t)MKT * HID;     // 7680*512
  ushort_t* Qs1 = Qs0 + (size_t)MQT * HID;     // 7680*512
  ushort_t* Qps = Qs1 + (size_t)MQT * HID;     // 7680*512 (qp scratch)
  ushort_t* gq = Qps + (size_t)MQT * HID;      // 7680*928
  ushort_t* gk = gq + (size_t)MQT * KP;        // 25600*928
  ushort_t* q2h_wt = gk + (size_t)MKT * KP;    // 928*512 (stored [N][K])
  ushort_t* k2h_wt = q2h_wt + (size_t)HID * KP;
  ushort_t* Wkt = k2h_wt + (size_t)HID * KP;   // 3*512*512
  ushort_t* Wqt = Wkt + (size_t)NLAYERS * HID * HID;
  ushort_t* p1wt = Wqt + (size_t)NLAYERS * HID * HID;   // 512*1024
  ushort_t* p2wt = p1wt + (size_t)HID * 1024;           // 384*512
  ushort_t* lastb = p2wt + (size_t)NOUTP * HID;         // 256*1024
  ushort_t* h1b = lastb + (size_t)BATCH * 1024;         // 256*512
  ushort_t* o2b = h1b + (size_t)BATCH * HID;            // 256*384

  // ---- pre-casts ----
  gather_all_k<<<MQT + MKT, 256, 0, stream>>>(qid, kid, emb, gq, gk);
  tcast10_k<<<dim3(16, 32, 10), 256, 0, stream>>>(
      q2h_w, k2h_w, Wk, Wq, p1w, p2w, q2h_wt, k2h_wt, Wkt, Wqt, p1wt, p2wt);

  // ---- input projections (merged q+k), fused proj_tan0, bf16 out ----
  mfma_gemm2<0, 1, 0, 1, 1, 0><<<dim3(HID / 128, MQT / 128 + MKT / 128), 256, 0, stream>>>(
      gq, q2h_wt, q2h_b, nullptr, Qs0, MQT / 128,
      gk, k2h_wt, k2h_b, nullptr, Ks0, nullptr, HID, KP, HID);

  // ---- layers in tangent space (3-buffer rotation) ----
  ushort_t* Kc = Ks0;
  ushort_t* Kn = Ks1;
  ushort_t* Qc = Qs0;
  ushort_t* Qn = Qs1;
  for (int i = 0; i < NLAYERS; ++i) {
    // kp = kt@Wk -> Kps ; qp = qt@Wq -> Qps
    mfma_gemm2<0, 0, 0, 1, 0, 0><<<dim3(HID / 128, MKT / 128 + MQT / 128), 256, 0, stream>>>(
        Kc, Wkt + (size_t)i * HID * HID, nullptr, nullptr, Kps, MKT / 128,
        Qc, Wqt + (size_t)i * HID * HID, nullptr, nullptr, Qps,
        nullptr, HID, HID, HID);
    // attention -> new state buffers (no in-place overwrite: 2 blocks/batch)
    att_fused_k<<<dim3(2, BATCH), 512, 0, stream>>>(Kps, Qps, Qc, Kc, Kn, Qn);
    ushort_t* t1 = Kc; Kc = Kn; Kn = t1;
    ushort_t* t2 = Qc; Qc = Qn; Qn = t2;
  }

  // ---- fused boundary (expproj + mean + logmap) -> lastb bf16 ----
  finale_k<<<BATCH, 512, 0, stream>>>(Kc, Qc, lastb, curv);

  // ---- head (all MFMA bf16) ----
  mfma_gemm2<0, 1, 0, 1, 0, 1><<<dim3(HID / 128, BATCH / 128), 256, 0, stream>>>(
      lastb, p1wt, p1b, nullptr, h1b, BATCH / 128,
      lastb, p1wt, p1b, nullptr, h1b, nullptr, HID, 1024, HID);
  mfma_gemm2<0, 1, 0, 1, 0, 0><<<dim3(NOUTP / 128, BATCH / 128), 256, 0, stream>>>(
      h1b, p2wt, p2b, nullptr, o2b, BATCH / 128,
      h1b, p2wt, p2b, nullptr, o2b, nullptr, NOUTP, HID, NOUT);
  // sim: B staged directly from f32 glove (cast in-register)
  mfma_gemm2<1, 0, 1, 0, 0, 0><<<dim3(NANS / 128, BATCH / 128), 256, 0, stream>>>(
      o2b, nullptr, nullptr, out, nullptr, BATCH / 128,
      o2b, nullptr, nullptr, out, nullptr, glove, NANS, NOUTP, NANS);
  logsoftmax_k<<<BATCH, 512, 0, stream>>>(out);
}

// Round 11
// 466.991 us; speedup vs baseline: 1.6132x; 1.2551x over previous
//
#include <hip/hip_runtime.h>
#include <math.h>

// Problem constants (from setup_inputs)
#define BATCH 256
#define NQ 30
#define NK 100
#define HID 512
#define WORD 300
#define KIN 900          // WORD*3
#define KP 928           // KIN padded to multiple of 32
#define NANS 32000
#define NOUT 300
#define NOUTP 384        // NOUT padded to multiple of 128 (MFMA N-tile)
#define NLAYERS 3
#define MQT (BATCH * NQ)   // 7680
#define MKT (BATCH * NK)   // 25600
#define SCALE 0.044194173824159216f  // 1/sqrt(512)
#define KTLD 520           // kt LDS row stride (512 + 8 pad)

typedef __attribute__((ext_vector_type(8))) short bf16x8;
typedef __attribute__((ext_vector_type(4))) float f32x4;
typedef unsigned short ushort_t;

__device__ __forceinline__ unsigned short f2bf(float f) {
  unsigned int u = __float_as_uint(f);
  u = (u + 0x7FFF + ((u >> 16) & 1)) >> 16;  // RNE
  return (unsigned short)u;
}
__device__ __forceinline__ float bf2f(unsigned short s) {
  return __uint_as_float(((unsigned int)s) << 16);
}

typedef const __attribute__((address_space(1))) unsigned int* gas_u32;
typedef __attribute__((address_space(3))) unsigned int* las_u32;
__device__ __forceinline__ void gld_lds16(const void* g, void* l) {
  __builtin_amdgcn_global_load_lds((gas_u32)g, (las_u32)l, 16, 0, 0);
}

// bijective XCD swizzle (m204)
__device__ __forceinline__ int xcd_swz_linear() {
  const int nwg = gridDim.x * gridDim.y;
  const int orig = blockIdx.y * gridDim.x + blockIdx.x;
  const int q = nwg >> 3, r = nwg & 7;
  const int xcd = orig & 7, idx = orig >> 3;
  return (xcd < r ? xcd * (q + 1) : r * (q + 1) + (xcd - r) * q) + idx;
}

// ---------------- reduction helpers ----------------
__device__ __forceinline__ float waveReduceSum(float v) {
#pragma unroll
  for (int o = 32; o > 0; o >>= 1) v += __shfl_xor(v, o);
  return v;
}
__device__ float blockReduceSum512(float v) {
  __shared__ float sm[8];
  int lane = threadIdx.x & 63, w = threadIdx.x >> 6;
  v = waveReduceSum(v);
  if (lane == 0) sm[w] = v;
  __syncthreads();
  float r = 0.f;
#pragma unroll
  for (int i = 0; i < 8; ++i) r += sm[i];
  __syncthreads();
  return r;
}

// cast 8 f32 from a glove row (length NOUT, zero-pad beyond) to bf16x8
__device__ __forceinline__ bf16x8 castrow8(const float* __restrict__ rowp, int kb) {
  union { ushort_t u[8]; bf16x8 v; } pk;
  if (kb + 8 <= NOUT) {
    float2 a0 = *(const float2*)(rowp + kb);
    float2 a1 = *(const float2*)(rowp + kb + 2);
    float2 a2 = *(const float2*)(rowp + kb + 4);
    float2 a3 = *(const float2*)(rowp + kb + 6);
    pk.u[0] = f2bf(a0.x); pk.u[1] = f2bf(a0.y);
    pk.u[2] = f2bf(a1.x); pk.u[3] = f2bf(a1.y);
    pk.u[4] = f2bf(a2.x); pk.u[5] = f2bf(a2.y);
    pk.u[6] = f2bf(a3.x); pk.u[7] = f2bf(a3.y);
  } else {
#pragma unroll
    for (int j = 0; j < 8; ++j) {
      const int kk = kb + j;
      pk.u[j] = (kk < NOUT) ? f2bf(rowp[kk]) : (ushort_t)0;
    }
  }
  return pk.v;
}

// ---------------- bf16 MFMA GEMM (dual operand-set, XCD-swizzled) ----------
// zsA/zsB/zsC: element strides applied per blockIdx.z (for batched M-GEMM).
template <int BF32B, int BIAS, int OUTF32, int OUTBF16, int ZC0, int RELU>
__global__ __launch_bounds__(256) void mfma_gemm2(
    const ushort_t* __restrict__ A1, const ushort_t* __restrict__ Bt1,
    const float* __restrict__ bias1, float* __restrict__ C1,
    ushort_t* __restrict__ Cb1, int M1b,
    const ushort_t* __restrict__ A2, const ushort_t* __restrict__ Bt2,
    const float* __restrict__ bias2, float* __restrict__ C2,
    ushort_t* __restrict__ Cb2, const float* __restrict__ Bf,
    size_t zsA, size_t zsB, size_t zsC,
    int N, int K, int nbias) {
  __shared__ __align__(16) ushort_t Abuf[128 * 32];
  __shared__ __align__(16) ushort_t Bbuf[128 * 32];
  const int wg = xcd_swz_linear();
  const int bx = wg % gridDim.x, by = wg / gridDim.x;
  const int z = blockIdx.z;
  const bool sel = (by >= M1b);
  const ushort_t* A = (sel ? A2 : A1) + z * zsA;
  const ushort_t* Bt = (sel ? Bt2 : Bt1) + z * zsB;
  const float* bias = sel ? bias2 : bias1;
  float* C = (sel ? C2 : C1);
  ushort_t* Cb = (sel ? Cb2 : Cb1);
  if (C) C += z * zsC;
  if (Cb) Cb += z * zsC;
  const int row0 = (sel ? (by - M1b) : by) * 128;
  const int col0 = bx * 128;

  const int tid = threadIdx.x;
  const int lane = tid & 63, w = tid >> 6;
  const int wr = w >> 1, wc = w & 1;
  const int s_r = lane & 15, s_kq = lane >> 4;

  const size_t a_src0 = (size_t)(row0 + (w * 2 + 0) * 16 + s_r) * K + s_kq * 8;
  const size_t a_src1 = (size_t)(row0 + (w * 2 + 1) * 16 + s_r) * K + s_kq * 8;
  const size_t b_src0 = (size_t)(col0 + (w * 2 + 0) * 16 + s_r) * K + s_kq * 8;
  const size_t b_src1 = (size_t)(col0 + (w * 2 + 1) * 16 + s_r) * K + s_kq * 8;
  ushort_t* a_dst0 = Abuf + (w * 2 + 0) * 512;
  ushort_t* a_dst1 = Abuf + (w * 2 + 1) * 512;
  ushort_t* b_dst0 = Bbuf + (w * 2 + 0) * 512;
  ushort_t* b_dst1 = Bbuf + (w * 2 + 1) * 512;
  const float* bf_row0 = BF32B ? (Bf + (size_t)(col0 + (w * 2 + 0) * 16 + s_r) * NOUT) : nullptr;
  const float* bf_row1 = BF32B ? (Bf + (size_t)(col0 + (w * 2 + 1) * 16 + s_r) * NOUT) : nullptr;

  f32x4 acc[4][4];
#pragma unroll
  for (int i = 0; i < 4; ++i)
#pragma unroll
    for (int j = 0; j < 4; ++j) acc[i][j] = (f32x4){0.f, 0.f, 0.f, 0.f};

  for (int k0 = 0; k0 < K; k0 += 32) {
    gld_lds16(A + a_src0 + k0, a_dst0);
    gld_lds16(A + a_src1 + k0, a_dst1);
    if (BF32B) {
      const int kb = k0 + s_kq * 8;
      *(bf16x8*)(b_dst0 + lane * 8) = castrow8(bf_row0, kb);
      *(bf16x8*)(b_dst1 + lane * 8) = castrow8(bf_row1, kb);
    } else {
      gld_lds16(Bt + b_src0 + k0, b_dst0);
      gld_lds16(Bt + b_src1 + k0, b_dst1);
    }
    __syncthreads();
    bf16x8 af[4], bfr[4];
#pragma unroll
    for (int mi = 0; mi < 4; ++mi)
      af[mi] = *(const bf16x8*)(Abuf + (wr * 4 + mi) * 512 + lane * 8);
#pragma unroll
    for (int nj = 0; nj < 4; ++nj)
      bfr[nj] = *(const bf16x8*)(Bbuf + (wc * 4 + nj) * 512 + lane * 8);
#pragma unroll
    for (int mi = 0; mi < 4; ++mi)
#pragma unroll
      for (int nj = 0; nj < 4; ++nj)
        acc[mi][nj] = __builtin_amdgcn_mfma_f32_16x16x32_bf16(
            af[mi], bfr[nj], acc[mi][nj], 0, 0, 0);
    __syncthreads();
  }

#pragma unroll
  for (int nj = 0; nj < 4; ++nj) {
    const int n = col0 + wc * 64 + nj * 16 + (lane & 15);
    const float bb = BIAS ? ((n < nbias) ? bias[n] : 0.f) : 0.f;
#pragma unroll
    for (int mi = 0; mi < 4; ++mi) {
      f32x4 v = acc[mi][nj];
#pragma unroll
      for (int r = 0; r < 4; ++r) {
        const int m = row0 + wr * 64 + mi * 16 + (lane >> 4) * 4 + r;
        float val = v[r] + bb;
        if (RELU) val = fmaxf(val, 0.f);
        if (ZC0 && n == 0) val = 0.f;
        if (OUTF32) C[(size_t)m * N + n] = val;
        if (OUTBF16) Cb[(size_t)m * N + n] = f2bf(val);
      }
    }
  }
}

// ---------------- pre-cast kernels ----------------
__global__ __launch_bounds__(256) void gather_all_k(
    const int* __restrict__ qid, const int* __restrict__ kid,
    const float* __restrict__ emb, ushort_t* __restrict__ gq,
    ushort_t* __restrict__ gk) {
  int m = blockIdx.x;
  const int* ids;
  ushort_t* outp;
  if (m < MQT) {
    ids = qid + m * 3;
    outp = gq + (size_t)m * KP;
  } else {
    m -= MQT;
    ids = kid + m * 3;
    outp = gk + (size_t)m * KP;
  }
  const int t = threadIdx.x;
  if (t >= KP / 4) return;
  const int k = t * 4;
  ushort4 o = make_ushort4(0, 0, 0, 0);
  if (k < KIN) {
    const int node = (k >= 600) ? 2 : ((k >= 300) ? 1 : 0);
    const int off = k - node * 300;
    const int id = ids[node];
    float4 v = *(const float4*)(emb + (size_t)id * 300 + off);
    if (v.x != v.x) v.x = 0.f;
    if (v.y != v.y) v.y = 0.f;
    if (v.z != v.z) v.z = 0.f;
    if (v.w != v.w) v.w = 0.f;
    o = make_ushort4(f2bf(v.x), f2bf(v.y), f2bf(v.z), f2bf(v.w));
  }
  *(ushort4*)(outp + k) = o;
}

// transpose-cast, 4 jobs: z=0 q2h, z=1 k2h, z=2 p1w, z=3 p2w
__global__ __launch_bounds__(256) void tcast4_k(
    const float* __restrict__ q2h_w, const float* __restrict__ k2h_w,
    const float* __restrict__ p1w, const float* __restrict__ p2w,
    ushort_t* __restrict__ q2h_wt, ushort_t* __restrict__ k2h_wt,
    ushort_t* __restrict__ p1wt, ushort_t* __restrict__ p2wt) {
  const int z = blockIdx.z;
  const float* src;
  ushort_t* dst;
  int R, Cc, Rp, Cp;
  if (z == 0)      { src = q2h_w; dst = q2h_wt; R = KIN;  Cc = HID;  Rp = KP;   Cp = HID; }
  else if (z == 1) { src = k2h_w; dst = k2h_wt; R = KIN;  Cc = HID;  Rp = KP;   Cp = HID; }
  else if (z == 2) { src = p1w; dst = p1wt; R = 1024; Cc = HID;  Rp = 1024; Cp = HID; }
  else             { src = p2w; dst = p2wt; R = HID;  Cc = NOUT; Rp = HID;  Cp = NOUTP; }
  const int r0 = blockIdx.y * 32, c0 = blockIdx.x * 32;
  if (r0 >= Rp || c0 >= Cp) return;
  __shared__ float t[32][33];
  const int tx = threadIdx.x & 31, ty = threadIdx.x >> 5;
#pragma unroll
  for (int i = 0; i < 4; ++i) {
    int r = r0 + ty + i * 8, c = c0 + tx;
    t[ty + i * 8][tx] = (r < R && c < Cc) ? src[(size_t)r * Cc + c] : 0.f;
  }
  __syncthreads();
#pragma unroll
  for (int i = 0; i < 4; ++i) {
    int c = c0 + ty + i * 8, r = r0 + tx;
    if (c < Cp && r < Rp) dst[(size_t)c * Rp + r] = f2bf(t[tx][ty + i * 8]);
  }
}

// plain row-cast of Wk[3] and Wq[3] (512x512 each) f32 -> bf16
__global__ __launch_bounds__(128) void castrows_k(
    const float* __restrict__ Wk, const float* __restrict__ Wq,
    ushort_t* __restrict__ Wkr, ushort_t* __restrict__ Wqr) {
  const int idx = blockIdx.x;  // 0..6*512-1
  const int mat = idx >> 9, row = idx & 511;
  const float* src = (mat < 3 ? Wk + (size_t)mat * HID * HID
                              : Wq + (size_t)(mat - 3) * HID * HID) + (size_t)row * HID;
  ushort_t* dst = (mat < 3 ? Wkr + (size_t)mat * HID * HID
                           : Wqr + (size_t)(mat - 3) * HID * HID) + (size_t)row * HID;
  const int k = threadIdx.x * 4;
  float4 v = *(const float4*)(src + k);
  *(ushort4*)(dst + k) = make_ushort4(f2bf(v.x), f2bf(v.y), f2bf(v.z), f2bf(v.w));
}

// ---------------- fused attention v4: LDS-resident kt/qt, 1 block/batch ----
// S = kt @ qp'^T  (qp' = qt @ (Wk Wq^T)^T precomputed by GEMM)
// LDS: kts [NK][KTLD] bf16 (104000B), qts [NQ][HID] bf16 (30720B),
//      S_lds [NK][32] f32 (12800B), PqT [NK][32] f32 (12800B) = 160320B
__global__ __launch_bounds__(512) void att_fused_k(
    const ushort_t* __restrict__ Qp, const ushort_t* __restrict__ Ktc,
    const ushort_t* __restrict__ Qc, ushort_t* __restrict__ Kn,
    ushort_t* __restrict__ Qn) {
  const int b = blockIdx.x;
  __shared__ float S_lds[NK][32];
  __shared__ float PqT[NK][32];
  __shared__ __align__(16) ushort_t kts[NK * KTLD];
  __shared__ __align__(16) ushort_t qts[NQ * HID];
  const int tid = threadIdx.x;
  const int w = tid >> 6, lane = tid & 63;
  const ushort_t* ktg = Ktc + (size_t)b * NK * HID;
  const ushort_t* qtg = Qc + (size_t)b * NQ * HID;

  // ---- stage kt (rows padded to KTLD) + qt, async; wave handles one row ----
  for (int e = tid; e < NK * 64; e += 512) {
    const int r = e >> 6, c16 = e & 63;
    gld_lds16(ktg + (size_t)r * HID + c16 * 8, kts + (size_t)r * KTLD + c16 * 8);
  }
  for (int e = tid; e < NQ * 64; e += 512) {
    const int r = e >> 6, c16 = e & 63;
    gld_lds16(qtg + (size_t)r * HID + c16 * 8, qts + (size_t)r * HID + c16 * 8);
  }
  __syncthreads();

  // ---- phase 1: S (waves 0-6), A-fragments from LDS kt ----
  if (w < 7) {
    const int r = lane & 15, kq = lane >> 4;
    const ushort_t* qpb = Qp + (size_t)b * NQ * HID;
    const int rowA = w * 16 + r;
    const int rowA_c = (rowA < NK) ? rowA : (NK - 1);
    const int qr1 = (16 + r) < NQ ? (16 + r) : NQ - 1;
    f32x4 a0 = {0.f, 0.f, 0.f, 0.f}, a1 = {0.f, 0.f, 0.f, 0.f};
    for (int k0 = 0; k0 < HID; k0 += 32) {
      bf16x8 af = *(const bf16x8*)(kts + (size_t)rowA_c * KTLD + k0 + kq * 8);
      bf16x8 b0 = *(const bf16x8*)(qpb + (size_t)r * HID + k0 + kq * 8);
      bf16x8 b1 = *(const bf16x8*)(qpb + (size_t)qr1 * HID + k0 + kq * 8);
      a0 = __builtin_amdgcn_mfma_f32_16x16x32_bf16(af, b0, a0, 0, 0, 0);
      a1 = __builtin_amdgcn_mfma_f32_16x16x32_bf16(af, b1, a1, 0, 0, 0);
    }
    const int q0 = lane & 15, mb = (lane >> 4) * 4;
#pragma unroll
    for (int rr = 0; rr < 4; ++rr) {
      const int mA = w * 16 + mb + rr;
      if (mA < NK) {
        S_lds[mA][q0] = a0[rr] * SCALE;
        if (q0 + 16 < NQ) S_lds[mA][q0 + 16] = a1[rr] * SCALE;
      }
    }
  }
  __syncthreads();
  // ---- phase 2a: Pq (softmax over kr, per q), stored TRANSPOSED ----
  if (tid < NQ) {
    const int q = tid;
    float m = -1e30f;
    for (int kr = 0; kr < NK; ++kr) m = fmaxf(m, S_lds[kr][q]);
    float s = 0.f;
    for (int kr = 0; kr < NK; ++kr) {
      float e = expf(S_lds[kr][q] - m);
      PqT[kr][q] = e;
      s += e;
    }
    float inv = 1.f / s;
    for (int kr = 0; kr < NK; ++kr) PqT[kr][q] *= inv;
  } else if (tid >= 32 && tid < 32 + NK) {
    const int kr = tid - 32;
    PqT[kr][30] = 0.f;
    PqT[kr][31] = 0.f;
  }
  __syncthreads();
  // ---- phase 2b: Pk rows in place ----
  if (tid < NK) {
    const int kr = tid;
    float m = -1e30f;
#pragma unroll
    for (int q = 0; q < NQ; ++q) m = fmaxf(m, S_lds[kr][q]);
    float s = 0.f;
    float e[NQ];
#pragma unroll
    for (int q = 0; q < NQ; ++q) {
      e[q] = expf(S_lds[kr][q] - m);
      s += e[q];
    }
    float inv = 1.f / s;
#pragma unroll
    for (int q = 0; q < NQ; ++q) S_lds[kr][q] = e[q] * inv;
    S_lds[kr][30] = 0.f;
    S_lds[kr][31] = 0.f;
  }
  __syncthreads();

  // ---- fused phase 3+4: thread owns column c = tid (512 cols) ----
  const int c = tid;
  float qx[32], ax[32];
#pragma unroll
  for (int q = 0; q < NQ; ++q) qx[q] = bf2f(qts[q * HID + c]);
  qx[30] = 0.f;
  qx[31] = 0.f;
#pragma unroll
  for (int i = 0; i < 32; ++i) ax[i] = 0.f;
  ushort_t* kout = Kn + (size_t)b * NK * HID;
  for (int kr = 0; kr < NK; ++kr) {
    const float kx = bf2f(kts[(size_t)kr * KTLD + c]);
    float sx = kx;
#pragma unroll
    for (int g = 0; g < 8; ++g) {
      float4 pk = *(const float4*)&S_lds[kr][g * 4];
      sx = fmaf(pk.x, qx[g * 4 + 0], sx);
      sx = fmaf(pk.y, qx[g * 4 + 1], sx);
      sx = fmaf(pk.z, qx[g * 4 + 2], sx);
      sx = fmaf(pk.w, qx[g * 4 + 3], sx);
      float4 pq = *(const float4*)&PqT[kr][g * 4];
      ax[g * 4 + 0] = fmaf(pq.x, kx, ax[g * 4 + 0]);
      ax[g * 4 + 1] = fmaf(pq.y, kx, ax[g * 4 + 1]);
      ax[g * 4 + 2] = fmaf(pq.z, kx, ax[g * 4 + 2]);
      ax[g * 4 + 3] = fmaf(pq.w, kx, ax[g * 4 + 3]);
    }
    kout[(size_t)kr * HID + c] = f2bf(sx);
  }
  ushort_t* qout = Qn + (size_t)b * NQ * HID;
#pragma unroll
  for (int q = 0; q < NQ; ++q)
    qout[(size_t)q * HID + c] = f2bf(ax[q] + qx[q]);
}

// ---------------- fused boundary: parallel row-norms ----------------
__global__ __launch_bounds__(512) void finale_k(
    const ushort_t* __restrict__ Kb, const ushort_t* __restrict__ Qb,
    ushort_t* __restrict__ lastb, const float* __restrict__ curv) {
  const int b = blockIdx.x, tid = threadIdx.x;
  const int w = tid >> 6, lane = tid & 63;
  const float c = curv[NLAYERS];
  const float Kc = 1.f / c, sqrtK = sqrtf(Kc);
  __shared__ float fsc[NK + NQ];
  __shared__ float fst[NK + NQ];
  const ushort_t* xkp = Kb + (size_t)b * NK * HID;
  const ushort_t* xqp = Qb + (size_t)b * NQ * HID;

  for (int r = w; r < NK + NQ; r += 8) {
    const ushort_t* row =
        (r < NK) ? (xkp + (size_t)r * HID) : (xqp + (size_t)(r - NK) * HID);
    bf16x8 v = *(const bf16x8*)(row + lane * 8);
    float ss = 0.f;
#pragma unroll
    for (int j = 0; j < 8; ++j) {
      float t = bf2f((unsigned short)v[j]);
      ss = fmaf(t, t, ss);
    }
    ss = waveReduceSum(ss);
    if (lane == 0) {
      float n = fmaxf(sqrtf(ss), 1e-15f);
      float f = sqrtK * sinhf(n / sqrtK) / n;
      fsc[r] = f;
      fst[r] = sqrtf(fmaxf(Kc + f * f * ss, 1e-7f));
    }
  }
  __syncthreads();

  float mk, mq;
  if (tid == 0) {
    float sk = 0.f, sq2 = 0.f;
    for (int r = 0; r < NK; ++r) sk += fst[r];
    for (int r = 0; r < NQ; ++r) sq2 += fst[NK + r];
    mk = sk;
    mq = sq2;
  } else {
    float sk = 0.f, sq2 = 0.f;
    for (int r = 0; r < NK; ++r)
      sk = fmaf(fsc[r], bf2f(xkp[(size_t)r * HID + tid]), sk);
    for (int r = 0; r < NQ; ++r)
      sq2 = fmaf(fsc[NK + r], bf2f(xqp[(size_t)r * HID + tid]), sq2);
    mk = sk;
    mq = sq2;
  }
  mk *= (1.f / NK);
  mq *= (1.f / NQ);

  float sq = ((tid == 0) ? 0.f : mk * mk) + mq * mq;
  float ssall = blockReduceSum512(sq);
  __shared__ float x0sh;
  if (tid == 0) x0sh = mk;
  __syncthreads();
  const float x0 = x0sh;
  const float n = fmaxf(sqrtf(ssall), 1e-15f);
  const float theta = fmaxf(x0 / sqrtK, 1.f + 1e-7f);
  const float rr = sqrtK * acoshf(theta) / n;
  ushort_t* ob = lastb + (size_t)b * 1024;
  ob[tid] = (tid == 0) ? (ushort_t)0 : f2bf(rr * mk);
  ob[512 + tid] = f2bf(rr * mq);
}

// ---------------- tail: 2-pass online log-softmax ----------------
__global__ __launch_bounds__(512) void logsoftmax_k(float* __restrict__ x) {
  const int b = blockIdx.x, tid = threadIdx.x;
  float4* row = (float4*)(x + (size_t)b * NANS);
  float m = -3.4e38f, s = 0.f;
  for (int i = tid; i < NANS / 4; i += 512) {
    float4 v = row[i];
    float lm = fmaxf(fmaxf(v.x, v.y), fmaxf(v.z, v.w));
    float nm = fmaxf(m, lm);
    s = s * expf(m - nm) + expf(v.x - nm) + expf(v.y - nm) +
        expf(v.z - nm) + expf(v.w - nm);
    m = nm;
  }
#pragma unroll
  for (int o = 32; o > 0; o >>= 1) {
    float mo = __shfl_xor(m, o);
    float so = __shfl_xor(s, o);
    float nm = fmaxf(m, mo);
    s = s * expf(m - nm) + so * expf(mo - nm);
    m = nm;
  }
  __shared__ float smm[8], sms[8];
  const int w = tid >> 6, lane = tid & 63;
  if (lane == 0) { smm[w] = m; sms[w] = s; }
  __syncthreads();
  float gm = smm[0], gs = sms[0];
#pragma unroll
  for (int i = 1; i < 8; ++i) {
    float nm = fmaxf(gm, smm[i]);
    gs = gs * expf(gm - nm) + sms[i] * expf(smm[i] - nm);
    gm = nm;
  }
  const float lse = gm + logf(gs);
  for (int i = tid; i < NANS / 4; i += 512) {
    float4 v = row[i];
    v.x -= lse; v.y -= lse; v.z -= lse; v.w -= lse;
    row[i] = v;
  }
}

// ---------------- launch ----------------
extern "C" void kernel_launch(void* const* d_in, const int* in_sizes, int n_in,
                              void* d_out, int out_size, void* d_ws, size_t ws_size,
                              hipStream_t stream) {
  const int* qid = (const int*)d_in[0];
  const int* kid = (const int*)d_in[1];
  const float* emb = (const float*)d_in[2];
  const float* q2h_w = (const float*)d_in[3];
  const float* q2h_b = (const float*)d_in[4];
  const float* k2h_w = (const float*)d_in[5];
  const float* k2h_b = (const float*)d_in[6];
  const float* Wk = (const float*)d_in[7];
  const float* Wq = (const float*)d_in[8];
  const float* curv = (const float*)d_in[9];
  const float* p1w = (const float*)d_in[10];
  const float* p1b = (const float*)d_in[11];
  const float* p2w = (const float*)d_in[12];
  const float* p2b = (const float*)d_in[13];
  const float* glove = (const float*)d_in[14];
  float* out = (float*)d_out;

  // ---- workspace layout (all bf16) ----
  ushort_t* u = (ushort_t*)d_ws;
  ushort_t* Ks0 = u;                           // 25600*512 (k-state ping)
  ushort_t* Ks1 = Ks0 + (size_t)MKT * HID;     // 25600*512 (k-state pong)
  ushort_t* Qs0 = Ks1 + (size_t)MKT * HID;     // 7680*512
  ushort_t* Qs1 = Qs0 + (size_t)MQT * HID;     // 7680*512
  ushort_t* Qps = Qs1 + (size_t)MQT * HID;     // 7680*512 (qp' scratch)
  ushort_t* gq = Qps + (size_t)MQT * HID;      // 7680*928
  ushort_t* gk = gq + (size_t)MQT * KP;        // 25600*928
  ushort_t* q2h_wt = gk + (size_t)MKT * KP;    // 928*512 (stored [N][K])
  ushort_t* k2h_wt = q2h_wt + (size_t)HID * KP;
  ushort_t* Wkr = k2h_wt + (size_t)HID * KP;   // 3*512*512 (row-major bf16)
  ushort_t* Wqr = Wkr + (size_t)NLAYERS * HID * HID;
  ushort_t* Mb = Wqr + (size_t)NLAYERS * HID * HID;    // 3*512*512 (M=Wk@Wq^T)
  ushort_t* p1wt = Mb + (size_t)NLAYERS * HID * HID;   // 512*1024
  ushort_t* p2wt = p1wt + (size_t)HID * 1024;          // 384*512
  ushort_t* lastb = p2wt + (size_t)NOUTP * HID;        // 256*1024
  ushort_t* h1b = lastb + (size_t)BATCH * 1024;        // 256*512
  ushort_t* o2b = h1b + (size_t)BATCH * HID;           // 256*384

  // ---- pre-casts ----
  gather_all_k<<<MQT + MKT, 256, 0, stream>>>(qid, kid, emb, gq, gk);
  tcast4_k<<<dim3(16, 32, 4), 256, 0, stream>>>(
      q2h_w, k2h_w, p1w, p2w, q2h_wt, k2h_wt, p1wt, p2wt);
  castrows_k<<<6 * HID, 128, 0, stream>>>(Wk, Wq, Wkr, Wqr);

  // ---- M_i = Wk_i @ Wq_i^T (bf16 out, row-major [c][d]), batched over z ----
  mfma_gemm2<0, 0, 0, 1, 0, 0><<<dim3(HID / 128, HID / 128, NLAYERS), 256, 0, stream>>>(
      Wkr, Wqr, nullptr, nullptr, Mb, HID / 128,
      Wkr, Wqr, nullptr, nullptr, Mb, nullptr,
      (size_t)HID * HID, (size_t)HID * HID, (size_t)HID * HID, HID, HID, HID);

  // ---- input projections (merged q+k), fused proj_tan0, bf16 out ----
  mfma_gemm2<0, 1, 0, 1, 1, 0><<<dim3(HID / 128, MQT / 128 + MKT / 128), 256, 0, stream>>>(
      gq, q2h_wt, q2h_b, nullptr, Qs0, MQT / 128,
      gk, k2h_wt, k2h_b, nullptr, Ks0, nullptr, 0, 0, 0, HID, KP, HID);

  // ---- layers in tangent space ----
  ushort_t* Kc = Ks0;
  ushort_t* Kn = Ks1;
  ushort_t* Qc = Qs0;
  ushort_t* Qn = Qs1;
  for (int i = 0; i < NLAYERS; ++i) {
    // qp' = qt @ M_i^T  -> Qps  (replaces BOTH kp and qp GEMMs)
    mfma_gemm2<0, 0, 0, 1, 0, 0><<<dim3(HID / 128, MQT / 128), 256, 0, stream>>>(
        Qc, Mb + (size_t)i * HID * HID, nullptr, nullptr, Qps, MQT / 128,
        Qc, Mb + (size_t)i * HID * HID, nullptr, nullptr, Qps, nullptr,
        0, 0, 0, HID, HID, HID);
    // attention: S = kt @ qp'^T, kt/qt LDS-resident
    att_fused_k<<<BATCH, 512, 0, stream>>>(Qps, Kc, Qc, Kn, Qn);
    ushort_t* t1 = Kc; Kc = Kn; Kn = t1;
    ushort_t* t2 = Qc; Qc = Qn; Qn = t2;
  }

  // ---- fused boundary (expproj + mean + logmap) -> lastb bf16 ----
  finale_k<<<BATCH, 512, 0, stream>>>(Kc, Qc, lastb, curv);

  // ---- head (all MFMA bf16) ----
  mfma_gemm2<0, 1, 0, 1, 0, 1><<<dim3(HID / 128, BATCH / 128), 256, 0, stream>>>(
      lastb, p1wt, p1b, nullptr, h1b, BATCH / 128,
      lastb, p1wt, p1b, nullptr, h1b, nullptr, 0, 0, 0, HID, 1024, HID);
  mfma_gemm2<0, 1, 0, 1, 0, 0><<<dim3(NOUTP / 128, BATCH / 128), 256, 0, stream>>>(
      h1b, p2wt, p2b, nullptr, o2b, BATCH / 128,
      h1b, p2wt, p2b, nullptr, o2b, nullptr, 0, 0, 0, NOUTP, HID, NOUT);
  // sim: B staged directly from f32 glove (cast in-register)
  mfma_gemm2<1, 0, 1, 0, 0, 0><<<dim3(NANS / 128, BATCH / 128), 256, 0, stream>>>(
      o2b, nullptr, nullptr, out, nullptr, BATCH / 128,
      o2b, nullptr, nullptr, out, nullptr, glove, 0, 0, 0, NANS, NOUTP, NANS);
  logsoftmax_k<<<BATCH, 512, 0, stream>>>(out);
}

// Round 12
// 451.042 us; speedup vs baseline: 1.6702x; 1.0354x over previous
//
#include <hip/hip_runtime.h>
#include <math.h>

// Problem constants (from setup_inputs)
#define BATCH 256
#define NQ 30
#define NK 100
#define HID 512
#define WORD 300
#define KIN 900          // WORD*3
#define KP 928           // KIN padded to multiple of 32
#define NANS 32000
#define NOUT 300
#define NOUTP 384        // NOUT padded to multiple of 128 (MFMA N-tile)
#define NLAYERS 3
#define MQT (BATCH * NQ)   // 7680
#define MKT (BATCH * NK)   // 25600
#define SCALE 0.044194173824159216f  // 1/sqrt(512)
#define KTLD 520           // kt LDS row stride (512 + 8 pad)

typedef __attribute__((ext_vector_type(8))) short bf16x8;
typedef __attribute__((ext_vector_type(4))) float f32x4;
typedef unsigned short ushort_t;

__device__ __forceinline__ unsigned short f2bf(float f) {
  unsigned int u = __float_as_uint(f);
  u = (u + 0x7FFF + ((u >> 16) & 1)) >> 16;  // RNE
  return (unsigned short)u;
}
__device__ __forceinline__ float bf2f(unsigned short s) {
  return __uint_as_float(((unsigned int)s) << 16);
}

typedef const __attribute__((address_space(1))) unsigned int* gas_u32;
typedef __attribute__((address_space(3))) unsigned int* las_u32;
__device__ __forceinline__ void gld_lds16(const void* g, void* l) {
  __builtin_amdgcn_global_load_lds((gas_u32)g, (las_u32)l, 16, 0, 0);
}

// bijective XCD swizzle (m204)
__device__ __forceinline__ int xcd_swz_linear() {
  const int nwg = gridDim.x * gridDim.y;
  const int orig = blockIdx.y * gridDim.x + blockIdx.x;
  const int q = nwg >> 3, r = nwg & 7;
  const int xcd = orig & 7, idx = orig >> 3;
  return (xcd < r ? xcd * (q + 1) : r * (q + 1) + (xcd - r) * q) + idx;
}

// ---------------- reduction helpers ----------------
__device__ __forceinline__ float waveReduceSum(float v) {
#pragma unroll
  for (int o = 32; o > 0; o >>= 1) v += __shfl_xor(v, o);
  return v;
}
__device__ float blockReduceSum512(float v) {
  __shared__ float sm[8];
  int lane = threadIdx.x & 63, w = threadIdx.x >> 6;
  v = waveReduceSum(v);
  if (lane == 0) sm[w] = v;
  __syncthreads();
  float r = 0.f;
#pragma unroll
  for (int i = 0; i < 8; ++i) r += sm[i];
  __syncthreads();
  return r;
}

// cast 8 f32 from a glove row (length NOUT, zero-pad beyond) to bf16x8
__device__ __forceinline__ bf16x8 castrow8(const float* __restrict__ rowp, int kb) {
  union { ushort_t u[8]; bf16x8 v; } pk;
  if (kb + 8 <= NOUT) {
    float2 a0 = *(const float2*)(rowp + kb);
    float2 a1 = *(const float2*)(rowp + kb + 2);
    float2 a2 = *(const float2*)(rowp + kb + 4);
    float2 a3 = *(const float2*)(rowp + kb + 6);
    pk.u[0] = f2bf(a0.x); pk.u[1] = f2bf(a0.y);
    pk.u[2] = f2bf(a1.x); pk.u[3] = f2bf(a1.y);
    pk.u[4] = f2bf(a2.x); pk.u[5] = f2bf(a2.y);
    pk.u[6] = f2bf(a3.x); pk.u[7] = f2bf(a3.y);
  } else {
#pragma unroll
    for (int j = 0; j < 8; ++j) {
      const int kk = kb + j;
      pk.u[j] = (kk < NOUT) ? f2bf(rowp[kk]) : (ushort_t)0;
    }
  }
  return pk.v;
}

// ---------------- bf16 MFMA GEMM v2: 2-phase double-buffered ----------
// T3-minimum schedule: issue next tile's global_load_lds BEFORE current
// tile's ds_read+MFMA; ONE barrier per K-step (drains vmcnt for the
// prefetched tile and protects the buffer being overwritten next step).
// zsA/zsB/zsC: element strides applied per blockIdx.z (batched M-GEMM).
template <int BF32B, int BIAS, int OUTF32, int OUTBF16, int ZC0, int RELU>
__global__ __launch_bounds__(256) void mfma_gemm2(
    const ushort_t* __restrict__ A1, const ushort_t* __restrict__ Bt1,
    const float* __restrict__ bias1, float* __restrict__ C1,
    ushort_t* __restrict__ Cb1, int M1b,
    const ushort_t* __restrict__ A2, const ushort_t* __restrict__ Bt2,
    const float* __restrict__ bias2, float* __restrict__ C2,
    ushort_t* __restrict__ Cb2, const float* __restrict__ Bf,
    size_t zsA, size_t zsB, size_t zsC,
    int N, int K, int nbias) {
  __shared__ __align__(16) ushort_t Abuf[2][128 * 32];
  __shared__ __align__(16) ushort_t Bbuf[2][128 * 32];
  const int wg = xcd_swz_linear();
  const int bx = wg % gridDim.x, by = wg / gridDim.x;
  const int z = blockIdx.z;
  const bool sel = (by >= M1b);
  const ushort_t* A = (sel ? A2 : A1) + z * zsA;
  const ushort_t* Bt = (sel ? Bt2 : Bt1) + z * zsB;
  const float* bias = sel ? bias2 : bias1;
  float* C = (sel ? C2 : C1);
  ushort_t* Cb = (sel ? Cb2 : Cb1);
  if (C) C += z * zsC;
  if (Cb) Cb += z * zsC;
  const int row0 = (sel ? (by - M1b) : by) * 128;
  const int col0 = bx * 128;

  const int tid = threadIdx.x;
  const int lane = tid & 63, w = tid >> 6;
  const int wr = w >> 1, wc = w & 1;
  const int s_r = lane & 15, s_kq = lane >> 4;

  const size_t a_src0 = (size_t)(row0 + (w * 2 + 0) * 16 + s_r) * K + s_kq * 8;
  const size_t a_src1 = (size_t)(row0 + (w * 2 + 1) * 16 + s_r) * K + s_kq * 8;
  const size_t b_src0 = (size_t)(col0 + (w * 2 + 0) * 16 + s_r) * K + s_kq * 8;
  const size_t b_src1 = (size_t)(col0 + (w * 2 + 1) * 16 + s_r) * K + s_kq * 8;
  const float* bf_row0 = BF32B ? (Bf + (size_t)(col0 + (w * 2 + 0) * 16 + s_r) * NOUT) : nullptr;
  const float* bf_row1 = BF32B ? (Bf + (size_t)(col0 + (w * 2 + 1) * 16 + s_r) * NOUT) : nullptr;

  auto stageAB = [&](int t, int bsel) {
    const int k0 = t * 32;
    gld_lds16(A + a_src0 + k0, Abuf[bsel] + (w * 2 + 0) * 512);
    gld_lds16(A + a_src1 + k0, Abuf[bsel] + (w * 2 + 1) * 512);
    if (BF32B) {
      const int kb = k0 + s_kq * 8;
      *(bf16x8*)(Bbuf[bsel] + (w * 2 + 0) * 512 + lane * 8) = castrow8(bf_row0, kb);
      *(bf16x8*)(Bbuf[bsel] + (w * 2 + 1) * 512 + lane * 8) = castrow8(bf_row1, kb);
    } else {
      gld_lds16(Bt + b_src0 + k0, Bbuf[bsel] + (w * 2 + 0) * 512);
      gld_lds16(Bt + b_src1 + k0, Bbuf[bsel] + (w * 2 + 1) * 512);
    }
  };

  f32x4 acc[4][4];
#pragma unroll
  for (int i = 0; i < 4; ++i)
#pragma unroll
    for (int j = 0; j < 4; ++j) acc[i][j] = (f32x4){0.f, 0.f, 0.f, 0.f};

  const int nt = K / 32;
  stageAB(0, 0);
  __syncthreads();  // tile 0 resident
  for (int t = 0; t < nt; ++t) {
    const int cur = t & 1;
    if (t + 1 < nt) stageAB(t + 1, cur ^ 1);  // async prefetch overlaps MFMA
    bf16x8 af[4], bfr[4];
#pragma unroll
    for (int mi = 0; mi < 4; ++mi)
      af[mi] = *(const bf16x8*)(Abuf[cur] + (wr * 4 + mi) * 512 + lane * 8);
#pragma unroll
    for (int nj = 0; nj < 4; ++nj)
      bfr[nj] = *(const bf16x8*)(Bbuf[cur] + (wc * 4 + nj) * 512 + lane * 8);
#pragma unroll
    for (int mi = 0; mi < 4; ++mi)
#pragma unroll
      for (int nj = 0; nj < 4; ++nj)
        acc[mi][nj] = __builtin_amdgcn_mfma_f32_16x16x32_bf16(
            af[mi], bfr[nj], acc[mi][nj], 0, 0, 0);
    __syncthreads();  // drains prefetch + protects buffer reuse
  }

#pragma unroll
  for (int nj = 0; nj < 4; ++nj) {
    const int n = col0 + wc * 64 + nj * 16 + (lane & 15);
    const float bb = BIAS ? ((n < nbias) ? bias[n] : 0.f) : 0.f;
#pragma unroll
    for (int mi = 0; mi < 4; ++mi) {
      f32x4 v = acc[mi][nj];
#pragma unroll
      for (int r = 0; r < 4; ++r) {
        const int m = row0 + wr * 64 + mi * 16 + (lane >> 4) * 4 + r;
        float val = v[r] + bb;
        if (RELU) val = fmaxf(val, 0.f);
        if (ZC0 && n == 0) val = 0.f;
        if (OUTF32) C[(size_t)m * N + n] = val;
        if (OUTBF16) Cb[(size_t)m * N + n] = f2bf(val);
      }
    }
  }
}

// ---------------- pre-cast kernels ----------------
__global__ __launch_bounds__(256) void gather_all_k(
    const int* __restrict__ qid, const int* __restrict__ kid,
    const float* __restrict__ emb, ushort_t* __restrict__ gq,
    ushort_t* __restrict__ gk) {
  int m = blockIdx.x;
  const int* ids;
  ushort_t* outp;
  if (m < MQT) {
    ids = qid + m * 3;
    outp = gq + (size_t)m * KP;
  } else {
    m -= MQT;
    ids = kid + m * 3;
    outp = gk + (size_t)m * KP;
  }
  const int t = threadIdx.x;
  if (t >= KP / 4) return;
  const int k = t * 4;
  ushort4 o = make_ushort4(0, 0, 0, 0);
  if (k < KIN) {
    const int node = (k >= 600) ? 2 : ((k >= 300) ? 1 : 0);
    const int off = k - node * 300;
    const int id = ids[node];
    float4 v = *(const float4*)(emb + (size_t)id * 300 + off);
    if (v.x != v.x) v.x = 0.f;
    if (v.y != v.y) v.y = 0.f;
    if (v.z != v.z) v.z = 0.f;
    if (v.w != v.w) v.w = 0.f;
    o = make_ushort4(f2bf(v.x), f2bf(v.y), f2bf(v.z), f2bf(v.w));
  }
  *(ushort4*)(outp + k) = o;
}

// transpose-cast, 4 jobs: z=0 q2h, z=1 k2h, z=2 p1w, z=3 p2w
__global__ __launch_bounds__(256) void tcast4_k(
    const float* __restrict__ q2h_w, const float* __restrict__ k2h_w,
    const float* __restrict__ p1w, const float* __restrict__ p2w,
    ushort_t* __restrict__ q2h_wt, ushort_t* __restrict__ k2h_wt,
    ushort_t* __restrict__ p1wt, ushort_t* __restrict__ p2wt) {
  const int z = blockIdx.z;
  const float* src;
  ushort_t* dst;
  int R, Cc, Rp, Cp;
  if (z == 0)      { src = q2h_w; dst = q2h_wt; R = KIN;  Cc = HID;  Rp = KP;   Cp = HID; }
  else if (z == 1) { src = k2h_w; dst = k2h_wt; R = KIN;  Cc = HID;  Rp = KP;   Cp = HID; }
  else if (z == 2) { src = p1w; dst = p1wt; R = 1024; Cc = HID;  Rp = 1024; Cp = HID; }
  else             { src = p2w; dst = p2wt; R = HID;  Cc = NOUT; Rp = HID;  Cp = NOUTP; }
  const int r0 = blockIdx.y * 32, c0 = blockIdx.x * 32;
  if (r0 >= Rp || c0 >= Cp) return;
  __shared__ float t[32][33];
  const int tx = threadIdx.x & 31, ty = threadIdx.x >> 5;
#pragma unroll
  for (int i = 0; i < 4; ++i) {
    int r = r0 + ty + i * 8, c = c0 + tx;
    t[ty + i * 8][tx] = (r < R && c < Cc) ? src[(size_t)r * Cc + c] : 0.f;
  }
  __syncthreads();
#pragma unroll
  for (int i = 0; i < 4; ++i) {
    int c = c0 + ty + i * 8, r = r0 + tx;
    if (c < Cp && r < Rp) dst[(size_t)c * Rp + r] = f2bf(t[tx][ty + i * 8]);
  }
}

// plain row-cast of Wk[3] and Wq[3] (512x512 each) f32 -> bf16
__global__ __launch_bounds__(128) void castrows_k(
    const float* __restrict__ Wk, const float* __restrict__ Wq,
    ushort_t* __restrict__ Wkr, ushort_t* __restrict__ Wqr) {
  const int idx = blockIdx.x;  // 0..6*512-1
  const int mat = idx >> 9, row = idx & 511;
  const float* src = (mat < 3 ? Wk + (size_t)mat * HID * HID
                              : Wq + (size_t)(mat - 3) * HID * HID) + (size_t)row * HID;
  ushort_t* dst = (mat < 3 ? Wkr + (size_t)mat * HID * HID
                           : Wqr + (size_t)(mat - 3) * HID * HID) + (size_t)row * HID;
  const int k = threadIdx.x * 4;
  float4 v = *(const float4*)(src + k);
  *(ushort4*)(dst + k) = make_ushort4(f2bf(v.x), f2bf(v.y), f2bf(v.z), f2bf(v.w));
}

// ---------------- fused attention v4: LDS-resident kt/qt, 1 block/batch ----
// S = kt @ qp'^T  (qp' = qt @ (Wk Wq^T)^T precomputed by GEMM)
__global__ __launch_bounds__(512) void att_fused_k(
    const ushort_t* __restrict__ Qp, const ushort_t* __restrict__ Ktc,
    const ushort_t* __restrict__ Qc, ushort_t* __restrict__ Kn,
    ushort_t* __restrict__ Qn) {
  const int b = blockIdx.x;
  __shared__ float S_lds[NK][32];
  __shared__ float PqT[NK][32];
  __shared__ __align__(16) ushort_t kts[NK * KTLD];
  __shared__ __align__(16) ushort_t qts[NQ * HID];
  const int tid = threadIdx.x;
  const int w = tid >> 6, lane = tid & 63;
  const ushort_t* ktg = Ktc + (size_t)b * NK * HID;
  const ushort_t* qtg = Qc + (size_t)b * NQ * HID;

  // ---- stage kt (rows padded to KTLD) + qt, async ----
  for (int e = tid; e < NK * 64; e += 512) {
    const int r = e >> 6, c16 = e & 63;
    gld_lds16(ktg + (size_t)r * HID + c16 * 8, kts + (size_t)r * KTLD + c16 * 8);
  }
  for (int e = tid; e < NQ * 64; e += 512) {
    const int r = e >> 6, c16 = e & 63;
    gld_lds16(qtg + (size_t)r * HID + c16 * 8, qts + (size_t)r * HID + c16 * 8);
  }
  __syncthreads();

  // ---- phase 1: S (waves 0-6), A-fragments from LDS kt ----
  if (w < 7) {
    const int r = lane & 15, kq = lane >> 4;
    const ushort_t* qpb = Qp + (size_t)b * NQ * HID;
    const int rowA = w * 16 + r;
    const int rowA_c = (rowA < NK) ? rowA : (NK - 1);
    const int qr1 = (16 + r) < NQ ? (16 + r) : NQ - 1;
    f32x4 a0 = {0.f, 0.f, 0.f, 0.f}, a1 = {0.f, 0.f, 0.f, 0.f};
    for (int k0 = 0; k0 < HID; k0 += 32) {
      bf16x8 af = *(const bf16x8*)(kts + (size_t)rowA_c * KTLD + k0 + kq * 8);
      bf16x8 b0 = *(const bf16x8*)(qpb + (size_t)r * HID + k0 + kq * 8);
      bf16x8 b1 = *(const bf16x8*)(qpb + (size_t)qr1 * HID + k0 + kq * 8);
      a0 = __builtin_amdgcn_mfma_f32_16x16x32_bf16(af, b0, a0, 0, 0, 0);
      a1 = __builtin_amdgcn_mfma_f32_16x16x32_bf16(af, b1, a1, 0, 0, 0);
    }
    const int q0 = lane & 15, mb = (lane >> 4) * 4;
#pragma unroll
    for (int rr = 0; rr < 4; ++rr) {
      const int mA = w * 16 + mb + rr;
      if (mA < NK) {
        S_lds[mA][q0] = a0[rr] * SCALE;
        if (q0 + 16 < NQ) S_lds[mA][q0 + 16] = a1[rr] * SCALE;
      }
    }
  }
  __syncthreads();
  // ---- phase 2a: Pq (softmax over kr, per q), stored TRANSPOSED ----
  if (tid < NQ) {
    const int q = tid;
    float m = -1e30f;
    for (int kr = 0; kr < NK; ++kr) m = fmaxf(m, S_lds[kr][q]);
    float s = 0.f;
    for (int kr = 0; kr < NK; ++kr) {
      float e = expf(S_lds[kr][q] - m);
      PqT[kr][q] = e;
      s += e;
    }
    float inv = 1.f / s;
    for (int kr = 0; kr < NK; ++kr) PqT[kr][q] *= inv;
  } else if (tid >= 32 && tid < 32 + NK) {
    const int kr = tid - 32;
    PqT[kr][30] = 0.f;
    PqT[kr][31] = 0.f;
  }
  __syncthreads();
  // ---- phase 2b: Pk rows in place ----
  if (tid < NK) {
    const int kr = tid;
    float m = -1e30f;
#pragma unroll
    for (int q = 0; q < NQ; ++q) m = fmaxf(m, S_lds[kr][q]);
    float s = 0.f;
    float e[NQ];
#pragma unroll
    for (int q = 0; q < NQ; ++q) {
      e[q] = expf(S_lds[kr][q] - m);
      s += e[q];
    }
    float inv = 1.f / s;
#pragma unroll
    for (int q = 0; q < NQ; ++q) S_lds[kr][q] = e[q] * inv;
    S_lds[kr][30] = 0.f;
    S_lds[kr][31] = 0.f;
  }
  __syncthreads();

  // ---- fused phase 3+4: thread owns column c = tid (512 cols) ----
  const int c = tid;
  float qx[32], ax[32];
#pragma unroll
  for (int q = 0; q < NQ; ++q) qx[q] = bf2f(qts[q * HID + c]);
  qx[30] = 0.f;
  qx[31] = 0.f;
#pragma unroll
  for (int i = 0; i < 32; ++i) ax[i] = 0.f;
  ushort_t* kout = Kn + (size_t)b * NK * HID;
  for (int kr = 0; kr < NK; ++kr) {
    const float kx = bf2f(kts[(size_t)kr * KTLD + c]);
    float sx = kx;
#pragma unroll
    for (int g = 0; g < 8; ++g) {
      float4 pk = *(const float4*)&S_lds[kr][g * 4];
      sx = fmaf(pk.x, qx[g * 4 + 0], sx);
      sx = fmaf(pk.y, qx[g * 4 + 1], sx);
      sx = fmaf(pk.z, qx[g * 4 + 2], sx);
      sx = fmaf(pk.w, qx[g * 4 + 3], sx);
      float4 pq = *(const float4*)&PqT[kr][g * 4];
      ax[g * 4 + 0] = fmaf(pq.x, kx, ax[g * 4 + 0]);
      ax[g * 4 + 1] = fmaf(pq.y, kx, ax[g * 4 + 1]);
      ax[g * 4 + 2] = fmaf(pq.z, kx, ax[g * 4 + 2]);
      ax[g * 4 + 3] = fmaf(pq.w, kx, ax[g * 4 + 3]);
    }
    kout[(size_t)kr * HID + c] = f2bf(sx);
  }
  ushort_t* qout = Qn + (size_t)b * NQ * HID;
#pragma unroll
  for (int q = 0; q < NQ; ++q)
    qout[(size_t)q * HID + c] = f2bf(ax[q] + qx[q]);
}

// ---------------- fused boundary: parallel row-norms ----------------
__global__ __launch_bounds__(512) void finale_k(
    const ushort_t* __restrict__ Kb, const ushort_t* __restrict__ Qb,
    ushort_t* __restrict__ lastb, const float* __restrict__ curv) {
  const int b = blockIdx.x, tid = threadIdx.x;
  const int w = tid >> 6, lane = tid & 63;
  const float c = curv[NLAYERS];
  const float Kc = 1.f / c, sqrtK = sqrtf(Kc);
  __shared__ float fsc[NK + NQ];
  __shared__ float fst[NK + NQ];
  const ushort_t* xkp = Kb + (size_t)b * NK * HID;
  const ushort_t* xqp = Qb + (size_t)b * NQ * HID;

  for (int r = w; r < NK + NQ; r += 8) {
    const ushort_t* row =
        (r < NK) ? (xkp + (size_t)r * HID) : (xqp + (size_t)(r - NK) * HID);
    bf16x8 v = *(const bf16x8*)(row + lane * 8);
    float ss = 0.f;
#pragma unroll
    for (int j = 0; j < 8; ++j) {
      float t = bf2f((unsigned short)v[j]);
      ss = fmaf(t, t, ss);
    }
    ss = waveReduceSum(ss);
    if (lane == 0) {
      float n = fmaxf(sqrtf(ss), 1e-15f);
      float f = sqrtK * sinhf(n / sqrtK) / n;
      fsc[r] = f;
      fst[r] = sqrtf(fmaxf(Kc + f * f * ss, 1e-7f));
    }
  }
  __syncthreads();

  float mk, mq;
  if (tid == 0) {
    float sk = 0.f, sq2 = 0.f;
    for (int r = 0; r < NK; ++r) sk += fst[r];
    for (int r = 0; r < NQ; ++r) sq2 += fst[NK + r];
    mk = sk;
    mq = sq2;
  } else {
    float sk = 0.f, sq2 = 0.f;
    for (int r = 0; r < NK; ++r)
      sk = fmaf(fsc[r], bf2f(xkp[(size_t)r * HID + tid]), sk);
    for (int r = 0; r < NQ; ++r)
      sq2 = fmaf(fsc[NK + r], bf2f(xqp[(size_t)r * HID + tid]), sq2);
    mk = sk;
    mq = sq2;
  }
  mk *= (1.f / NK);
  mq *= (1.f / NQ);

  float sq = ((tid == 0) ? 0.f : mk * mk) + mq * mq;
  float ssall = blockReduceSum512(sq);
  __shared__ float x0sh;
  if (tid == 0) x0sh = mk;
  __syncthreads();
  const float x0 = x0sh;
  const float n = fmaxf(sqrtf(ssall), 1e-15f);
  const float theta = fmaxf(x0 / sqrtK, 1.f + 1e-7f);
  const float rr = sqrtK * acoshf(theta) / n;
  ushort_t* ob = lastb + (size_t)b * 1024;
  ob[tid] = (tid == 0) ? (ushort_t)0 : f2bf(rr * mk);
  ob[512 + tid] = f2bf(rr * mq);
}

// ---------------- tail: 2-pass online log-softmax ----------------
__global__ __launch_bounds__(512) void logsoftmax_k(float* __restrict__ x) {
  const int b = blockIdx.x, tid = threadIdx.x;
  float4* row = (float4*)(x + (size_t)b * NANS);
  float m = -3.4e38f, s = 0.f;
  for (int i = tid; i < NANS / 4; i += 512) {
    float4 v = row[i];
    float lm = fmaxf(fmaxf(v.x, v.y), fmaxf(v.z, v.w));
    float nm = fmaxf(m, lm);
    s = s * expf(m - nm) + expf(v.x - nm) + expf(v.y - nm) +
        expf(v.z - nm) + expf(v.w - nm);
    m = nm;
  }
#pragma unroll
  for (int o = 32; o > 0; o >>= 1) {
    float mo = __shfl_xor(m, o);
    float so = __shfl_xor(s, o);
    float nm = fmaxf(m, mo);
    s = s * expf(m - nm) + so * expf(mo - nm);
    m = nm;
  }
  __shared__ float smm[8], sms[8];
  const int w = tid >> 6, lane = tid & 63;
  if (lane == 0) { smm[w] = m; sms[w] = s; }
  __syncthreads();
  float gm = smm[0], gs = sms[0];
#pragma unroll
  for (int i = 1; i < 8; ++i) {
    float nm = fmaxf(gm, smm[i]);
    gs = gs * expf(gm - nm) + sms[i] * expf(smm[i] - nm);
    gm = nm;
  }
  const float lse = gm + logf(gs);
  for (int i = tid; i < NANS / 4; i += 512) {
    float4 v = row[i];
    v.x -= lse; v.y -= lse; v.z -= lse; v.w -= lse;
    row[i] = v;
  }
}

// ---------------- launch ----------------
extern "C" void kernel_launch(void* const* d_in, const int* in_sizes, int n_in,
                              void* d_out, int out_size, void* d_ws, size_t ws_size,
                              hipStream_t stream) {
  const int* qid = (const int*)d_in[0];
  const int* kid = (const int*)d_in[1];
  const float* emb = (const float*)d_in[2];
  const float* q2h_w = (const float*)d_in[3];
  const float* q2h_b = (const float*)d_in[4];
  const float* k2h_w = (const float*)d_in[5];
  const float* k2h_b = (const float*)d_in[6];
  const float* Wk = (const float*)d_in[7];
  const float* Wq = (const float*)d_in[8];
  const float* curv = (const float*)d_in[9];
  const float* p1w = (const float*)d_in[10];
  const float* p1b = (const float*)d_in[11];
  const float* p2w = (const float*)d_in[12];
  const float* p2b = (const float*)d_in[13];
  const float* glove = (const float*)d_in[14];
  float* out = (float*)d_out;

  // ---- workspace layout (all bf16) ----
  ushort_t* u = (ushort_t*)d_ws;
  ushort_t* Ks0 = u;                           // 25600*512 (k-state ping)
  ushort_t* Ks1 = Ks0 + (size_t)MKT * HID;     // 25600*512 (k-state pong)
  ushort_t* Qs0 = Ks1 + (size_t)MKT * HID;     // 7680*512
  ushort_t* Qs1 = Qs0 + (size_t)MQT * HID;     // 7680*512
  ushort_t* Qps = Qs1 + (size_t)MQT * HID;     // 7680*512 (qp' scratch)
  ushort_t* gq = Qps + (size_t)MQT * HID;      // 7680*928
  ushort_t* gk = gq + (size_t)MQT * KP;        // 25600*928
  ushort_t* q2h_wt = gk + (size_t)MKT * KP;    // 928*512 (stored [N][K])
  ushort_t* k2h_wt = q2h_wt + (size_t)HID * KP;
  ushort_t* Wkr = k2h_wt + (size_t)HID * KP;   // 3*512*512 (row-major bf16)
  ushort_t* Wqr = Wkr + (size_t)NLAYERS * HID * HID;
  ushort_t* Mb = Wqr + (size_t)NLAYERS * HID * HID;    // 3*512*512 (M=Wk@Wq^T)
  ushort_t* p1wt = Mb + (size_t)NLAYERS * HID * HID;   // 512*1024
  ushort_t* p2wt = p1wt + (size_t)HID * 1024;          // 384*512
  ushort_t* lastb = p2wt + (size_t)NOUTP * HID;        // 256*1024
  ushort_t* h1b = lastb + (size_t)BATCH * 1024;        // 256*512
  ushort_t* o2b = h1b + (size_t)BATCH * HID;           // 256*384

  // ---- pre-casts ----
  gather_all_k<<<MQT + MKT, 256, 0, stream>>>(qid, kid, emb, gq, gk);
  tcast4_k<<<dim3(16, 32, 4), 256, 0, stream>>>(
      q2h_w, k2h_w, p1w, p2w, q2h_wt, k2h_wt, p1wt, p2wt);
  castrows_k<<<6 * HID, 128, 0, stream>>>(Wk, Wq, Wkr, Wqr);

  // ---- M_i = Wk_i @ Wq_i^T (bf16 out, row-major [c][d]), batched over z ----
  mfma_gemm2<0, 0, 0, 1, 0, 0><<<dim3(HID / 128, HID / 128, NLAYERS), 256, 0, stream>>>(
      Wkr, Wqr, nullptr, nullptr, Mb, HID / 128,
      Wkr, Wqr, nullptr, nullptr, Mb, nullptr,
      (size_t)HID * HID, (size_t)HID * HID, (size_t)HID * HID, HID, HID, HID);

  // ---- input projections (merged q+k), fused proj_tan0, bf16 out ----
  mfma_gemm2<0, 1, 0, 1, 1, 0><<<dim3(HID / 128, MQT / 128 + MKT / 128), 256, 0, stream>>>(
      gq, q2h_wt, q2h_b, nullptr, Qs0, MQT / 128,
      gk, k2h_wt, k2h_b, nullptr, Ks0, nullptr, 0, 0, 0, HID, KP, HID);

  // ---- layers in tangent space ----
  ushort_t* Kc = Ks0;
  ushort_t* Kn = Ks1;
  ushort_t* Qc = Qs0;
  ushort_t* Qn = Qs1;
  for (int i = 0; i < NLAYERS; ++i) {
    // qp' = qt @ M_i^T  -> Qps  (replaces BOTH kp and qp GEMMs)
    mfma_gemm2<0, 0, 0, 1, 0, 0><<<dim3(HID / 128, MQT / 128), 256, 0, stream>>>(
        Qc, Mb + (size_t)i * HID * HID, nullptr, nullptr, Qps, MQT / 128,
        Qc, Mb + (size_t)i * HID * HID, nullptr, nullptr, Qps, nullptr,
        0, 0, 0, HID, HID, HID);
    // attention: S = kt @ qp'^T, kt/qt LDS-resident
    att_fused_k<<<BATCH, 512, 0, stream>>>(Qps, Kc, Qc, Kn, Qn);
    ushort_t* t1 = Kc; Kc = Kn; Kn = t1;
    ushort_t* t2 = Qc; Qc = Qn; Qn = t2;
  }

  // ---- fused boundary (expproj + mean + logmap) -> lastb bf16 ----
  finale_k<<<BATCH, 512, 0, stream>>>(Kc, Qc, lastb, curv);

  // ---- head (all MFMA bf16) ----
  mfma_gemm2<0, 1, 0, 1, 0, 1><<<dim3(HID / 128, BATCH / 128), 256, 0, stream>>>(
      lastb, p1wt, p1b, nullptr, h1b, BATCH / 128,
      lastb, p1wt, p1b, nullptr, h1b, nullptr, 0, 0, 0, HID, 1024, HID);
  mfma_gemm2<0, 1, 0, 1, 0, 0><<<dim3(NOUTP / 128, BATCH / 128), 256, 0, stream>>>(
      h1b, p2wt, p2b, nullptr, o2b, BATCH / 128,
      h1b, p2wt, p2b, nullptr, o2b, nullptr, 0, 0, 0, NOUTP, HID, NOUT);
  // sim: B staged directly from f32 glove (cast in-register)
  mfma_gemm2<1, 0, 1, 0, 0, 0><<<dim3(NANS / 128, BATCH / 128), 256, 0, stream>>>(
      o2b, nullptr, nullptr, out, nullptr, BATCH / 128,
      o2b, nullptr, nullptr, out, nullptr, glove, 0, 0, 0, NANS, NOUTP, NANS);
  logsoftmax_k<<<BATCH, 512, 0, stream>>>(out);
}